// Round 1
// baseline (1658.878 us; speedup 1.0000x reference)
//
#include <hip/hip_runtime.h>

#define NFEAT 78
#define NTYPES 44
#define NFIX 34
#define DIM 128
#define LIN_K 162   // DIM + NFIX

// ---------- device helpers ----------
__device__ __forceinline__ void atom_add_f32(float* p, float v) {
#if defined(__AMDGCN__)
    unsafeAtomicAdd(p, v);   // HW global_atomic_add_f32 (gfx90a+)
#else
    atomicAdd(p, v);
#endif
}

// ---------- kernel 1: h = relu(concat(emb[argmax(x[:, :44])], x[:,44:]) @ lin_W^T + b) ----------
__global__ __launch_bounds__(128) void k_embed_linear(
    const float* __restrict__ x, const float* __restrict__ emb,
    const float* __restrict__ W, const float* __restrict__ b,
    float* __restrict__ h, int N)
{
    __shared__ float s_x[8][NFEAT];
    __shared__ float s_in[8][LIN_K];
    __shared__ int   s_idx[8];
    const int tid = threadIdx.x;
    const int node0 = blockIdx.x * 8;

    for (int q = tid; q < 8 * NFEAT; q += 128) {
        int j = q / NFEAT, k = q - j * NFEAT;
        int n = node0 + j;
        s_x[j][k] = (n < N) ? x[(long)n * NFEAT + k] : 0.0f;
    }
    __syncthreads();
    if (tid < 8) {
        float best = s_x[tid][0]; int bi = 0;
        for (int k = 1; k < NTYPES; ++k) {
            float v = s_x[tid][k];
            if (v > best) { best = v; bi = k; }   // strict > keeps first occurrence (jnp.argmax)
        }
        s_idx[tid] = bi;
    }
    __syncthreads();
    for (int q = tid; q < 8 * DIM; q += 128) {
        int j = q >> 7, d = q & 127;
        s_in[j][d] = emb[s_idx[j] * DIM + d];
    }
    for (int q = tid; q < 8 * NFIX; q += 128) {
        int j = q / NFIX, c = q - j * NFIX;
        s_in[j][DIM + c] = s_x[j][NTYPES + c];
    }
    __syncthreads();

    const int d = tid;
    float acc[8];
    const float bias = b[d];
    #pragma unroll
    for (int j = 0; j < 8; ++j) acc[j] = bias;
    const float* wrow = W + (long)d * LIN_K;
    for (int k = 0; k < LIN_K; ++k) {
        float w = wrow[k];
        #pragma unroll
        for (int j = 0; j < 8; ++j) acc[j] = fmaf(s_in[j][k], w, acc[j]);
    }
    #pragma unroll
    for (int j = 0; j < 8; ++j) {
        int n = node0 + j;
        if (n < N) h[(long)n * DIM + d] = fmaxf(acc[j], 0.0f);
    }
}

// ---------- degree / norm ----------
__global__ void k_deg_init(float* __restrict__ deg, int N) {
    int i = blockIdx.x * 256 + threadIdx.x;
    if (i < N) deg[i] = 1.0f;                    // self-loop
}
__global__ void k_deg_count(const int* __restrict__ dst, float* __restrict__ deg, int E) {
    int e = blockIdx.x * 256 + threadIdx.x;
    if (e < E) atom_add_f32(&deg[dst[e]], 1.0f); // exact: integer-valued floats
}
__global__ void k_dinv(float* __restrict__ deg, int N) {
    int i = blockIdx.x * 256 + threadIdx.x;
    if (i < N) deg[i] = rsqrtf(deg[i]);          // deg >= 1 always
}

// ---------- GCN linear: ht = hin @ W^T ; accout = ht * dinv^2 (self-loop init) ----------
// hin may alias ht or accout: each block stages its own 8 rows to LDS first,
// then writes only those same rows.
__global__ __launch_bounds__(128) void k_gcn_gemm(
    const float* __restrict__ hin, const float* __restrict__ W,
    const float* __restrict__ dinv,
    float* __restrict__ ht, float* __restrict__ accout, int N)
{
    __shared__ float s_in[8][DIM];
    const int tid = threadIdx.x;
    const int node0 = blockIdx.x * 8;

    for (int q = tid; q < 8 * DIM; q += 128) {
        int j = q >> 7, k = q & 127;
        int n = node0 + j;
        s_in[j][k] = (n < N) ? hin[(long)n * DIM + k] : 0.0f;
    }
    __syncthreads();

    const int d = tid;
    float acc[8];
    #pragma unroll
    for (int j = 0; j < 8; ++j) acc[j] = 0.0f;
    const float* wrow = W + (long)d * DIM;
    for (int k = 0; k < DIM; ++k) {
        float w = wrow[k];
        #pragma unroll
        for (int j = 0; j < 8; ++j) acc[j] = fmaf(s_in[j][k], w, acc[j]);
    }
    #pragma unroll
    for (int j = 0; j < 8; ++j) {
        int n = node0 + j;
        if (n < N) {
            float v = acc[j];
            ht[(long)n * DIM + d] = v;
            float di = dinv[n];
            accout[(long)n * DIM + d] = v * di * di;
        }
    }
}

// ---------- edge scatter: acc[dst] += ht[src] * dinv[src]*dinv[dst] ----------
// one wave (64 lanes) per edge; float2 per lane (128 dims)
__global__ __launch_bounds__(256) void k_edge_scatter(
    const int* __restrict__ src, const int* __restrict__ dst,
    const float* __restrict__ dinv, const float* __restrict__ ht,
    float* __restrict__ acc, int E)
{
    int wave = (int)((blockIdx.x * 256 + threadIdx.x) >> 6);
    int lane = threadIdx.x & 63;
    if (wave >= E) return;
    int s = src[wave], t = dst[wave];
    float nrm = dinv[s] * dinv[t];
    const float2* hs = (const float2*)(ht + (long)s * DIM);
    float2 v = hs[lane];
    float* ad = acc + (long)t * DIM;
    atom_add_f32(&ad[2 * lane],     v.x * nrm);
    atom_add_f32(&ad[2 * lane + 1], v.y * nrm);
}

// ---------- epilogue: a = relu(a + b[d]) ----------
__global__ void k_bias_relu(float* __restrict__ a, const float* __restrict__ b, int total) {
    int i = blockIdx.x * 256 + threadIdx.x;
    if (i < total) {
        a[i] = fmaxf(a[i] + b[i & 127], 0.0f);
    }
}

extern "C" void kernel_launch(void* const* d_in, const int* in_sizes, int n_in,
                              void* d_out, int out_size, void* d_ws, size_t ws_size,
                              hipStream_t stream) {
    const float* x     = (const float*)d_in[0];
    const int*   edge  = (const int*)d_in[1];
    // d_in[2] = batch (unused by the reference output)
    const float* emb   = (const float*)d_in[3];
    const float* lin_W = (const float*)d_in[4];
    const float* lin_b = (const float*)d_in[5];
    const float* g1W   = (const float*)d_in[6];
    const float* g1b   = (const float*)d_in[7];
    const float* g2W   = (const float*)d_in[8];
    const float* g2b   = (const float*)d_in[9];
    float* out = (float*)d_out;

    const int N = in_sizes[0] / NFEAT;
    const int E = in_sizes[1] / 2;
    const int* esrc = edge;
    const int* edst = edge + E;

    float* ws0  = (float*)d_ws;                   // N*DIM floats (h / ht scratch)
    float* dinv = ws0 + (size_t)N * DIM;          // N floats

    const int nb8   = (N + 7) / 8;
    const int nbN   = (N + 255) / 256;
    const int nbE   = (E + 255) / 256;
    const int nbND  = (N * DIM + 255) / 256;
    const int nbEW  = (E * 64 + 255) / 256;       // one wave per edge

    // h1 = relu(lin(...)) -> ws0
    k_embed_linear<<<nb8, 128, 0, stream>>>(x, emb, lin_W, lin_b, ws0, N);

    // dinv = rsqrt(in_degree + 1)
    k_deg_init<<<nbN, 256, 0, stream>>>(dinv, N);
    k_deg_count<<<nbE, 256, 0, stream>>>(edst, dinv, E);
    k_dinv<<<nbN, 256, 0, stream>>>(dinv, N);

    // layer 1: ht -> ws0 (in place), self-loop-init acc -> d_out
    k_gcn_gemm<<<nb8, 128, 0, stream>>>(ws0, g1W, dinv, ws0, out, N);
    k_edge_scatter<<<nbEW, 256, 0, stream>>>(esrc, edst, dinv, ws0, out, E);
    k_bias_relu<<<nbND, 256, 0, stream>>>(out, g1b, N * DIM);

    // layer 2: ht -> ws0, self-loop-init acc -> d_out (in place)
    k_gcn_gemm<<<nb8, 128, 0, stream>>>(out, g2W, dinv, ws0, out, N);
    k_edge_scatter<<<nbEW, 256, 0, stream>>>(esrc, edst, dinv, ws0, out, E);
    k_bias_relu<<<nbND, 256, 0, stream>>>(out, g2b, N * DIM);
}

// Round 2
// 489.902 us; speedup vs baseline: 3.3861x; 3.3861x over previous
//
#include <hip/hip_runtime.h>

#define NFEAT 78
#define NTYPES 44
#define NFIX 34
#define DIM 128
#define LIN_K 162   // DIM + NFIX
#define SCAN_BS 256

// ---------- kernel 1: h = relu(concat(emb[argmax(x[:, :44])], x[:,44:]) @ lin_W^T + b) ----------
__global__ __launch_bounds__(128) void k_embed_linear(
    const float* __restrict__ x, const float* __restrict__ emb,
    const float* __restrict__ W, const float* __restrict__ b,
    float* __restrict__ h, int N)
{
    __shared__ float s_x[8][NFEAT];
    __shared__ float s_in[8][LIN_K];
    __shared__ int   s_idx[8];
    const int tid = threadIdx.x;
    const int node0 = blockIdx.x * 8;

    for (int q = tid; q < 8 * NFEAT; q += 128) {
        int j = q / NFEAT, k = q - j * NFEAT;
        int n = node0 + j;
        s_x[j][k] = (n < N) ? x[(long)n * NFEAT + k] : 0.0f;
    }
    __syncthreads();
    if (tid < 8) {
        float best = s_x[tid][0]; int bi = 0;
        for (int k = 1; k < NTYPES; ++k) {
            float v = s_x[tid][k];
            if (v > best) { best = v; bi = k; }   // strict > keeps first occurrence (jnp.argmax)
        }
        s_idx[tid] = bi;
    }
    __syncthreads();
    for (int q = tid; q < 8 * DIM; q += 128) {
        int j = q >> 7, d = q & 127;
        s_in[j][d] = emb[s_idx[j] * DIM + d];
    }
    for (int q = tid; q < 8 * NFIX; q += 128) {
        int j = q / NFIX, c = q - j * NFIX;
        s_in[j][DIM + c] = s_x[j][NTYPES + c];
    }
    __syncthreads();

    const int d = tid;
    float acc[8];
    const float bias = b[d];
    #pragma unroll
    for (int j = 0; j < 8; ++j) acc[j] = bias;
    const float* wrow = W + (long)d * LIN_K;
    for (int k = 0; k < LIN_K; ++k) {
        float w = wrow[k];
        #pragma unroll
        for (int j = 0; j < 8; ++j) acc[j] = fmaf(s_in[j][k], w, acc[j]);
    }
    #pragma unroll
    for (int j = 0; j < 8; ++j) {
        int n = node0 + j;
        if (n < N) h[(long)n * DIM + d] = fmaxf(acc[j], 0.0f);
    }
}

// ---------- CSR build ----------
__global__ void k_zero_int(int* __restrict__ p, int n) {
    int i = blockIdx.x * 256 + threadIdx.x;
    if (i < n) p[i] = 0;
}
__global__ void k_count(const int* __restrict__ dst, int* __restrict__ cnt, int E) {
    int e = blockIdx.x * 256 + threadIdx.x;
    if (e < E) atomicAdd(&cnt[dst[e]], 1);
}
// per-block sums of cnt
__global__ __launch_bounds__(SCAN_BS) void k_blocksum(
    const int* __restrict__ cnt, int* __restrict__ partial, int N)
{
    __shared__ int s[SCAN_BS];
    int t = threadIdx.x, i = blockIdx.x * SCAN_BS + t;
    s[t] = (i < N) ? cnt[i] : 0;
    __syncthreads();
    for (int off = SCAN_BS / 2; off > 0; off >>= 1) {
        if (t < off) s[t] += s[t + off];
        __syncthreads();
    }
    if (t == 0) partial[blockIdx.x] = s[0];
}
// single-block exclusive scan of partials (nb <= SCAN_BS required; nb=196 for N=50k)
__global__ __launch_bounds__(SCAN_BS) void k_scan_partials(int* __restrict__ partial, int nb) {
    __shared__ int s[SCAN_BS];
    int t = threadIdx.x;
    int v = (t < nb) ? partial[t] : 0;
    s[t] = v;
    __syncthreads();
    for (int off = 1; off < SCAN_BS; off <<= 1) {
        int u = (t >= off) ? s[t - off] : 0;
        __syncthreads();
        s[t] += u;
        __syncthreads();
    }
    if (t < nb) partial[t] = s[t] - v;   // exclusive
}
// row_off[i] = global exclusive scan; cursor[i] = 0; row_off[N] = E
__global__ __launch_bounds__(SCAN_BS) void k_row_off(
    const int* __restrict__ cnt, const int* __restrict__ partial,
    int* __restrict__ row_off, int* __restrict__ cursor, int N, int E)
{
    __shared__ int s[SCAN_BS];
    int t = threadIdx.x, i = blockIdx.x * SCAN_BS + t;
    int c = (i < N) ? cnt[i] : 0;
    s[t] = c;
    __syncthreads();
    for (int off = 1; off < SCAN_BS; off <<= 1) {
        int u = (t >= off) ? s[t - off] : 0;
        __syncthreads();
        s[t] += u;
        __syncthreads();
    }
    if (i < N) {
        row_off[i] = (s[t] - c) + partial[blockIdx.x];
        cursor[i] = 0;
    }
    if (blockIdx.x == 0 && t == 0) row_off[N] = E;
}
__global__ void k_fill(const int* __restrict__ src, const int* __restrict__ dst,
                       const int* __restrict__ row_off, int* __restrict__ cursor,
                       int* __restrict__ csr, int E)
{
    int e = blockIdx.x * 256 + threadIdx.x;
    if (e < E) {
        int t = dst[e];
        int pos = atomicAdd(&cursor[t], 1);
        csr[row_off[t] + pos] = src[e];
    }
}
__global__ void k_dinv(const int* __restrict__ row_off, float* __restrict__ dinv, int N) {
    int i = blockIdx.x * 256 + threadIdx.x;
    if (i < N) {
        int deg = row_off[i + 1] - row_off[i] + 1;   // + self-loop
        dinv[i] = rsqrtf((float)deg);
    }
}

// ---------- GCN linear: hs = (hin @ W^T) * dinv[n]  (pre-scaled by source norm) ----------
// hin may alias hs: each block stages its own 8 rows to LDS before writing them.
__global__ __launch_bounds__(128) void k_gcn_gemm(
    const float* __restrict__ hin, const float* __restrict__ W,
    const float* __restrict__ dinv, float* __restrict__ hs, int N)
{
    __shared__ float s_in[8][DIM];
    const int tid = threadIdx.x;
    const int node0 = blockIdx.x * 8;

    for (int q = tid; q < 8 * DIM; q += 128) {
        int j = q >> 7, k = q & 127;
        int n = node0 + j;
        s_in[j][k] = (n < N) ? hin[(long)n * DIM + k] : 0.0f;
    }
    __syncthreads();

    const int d = tid;
    float acc[8];
    #pragma unroll
    for (int j = 0; j < 8; ++j) acc[j] = 0.0f;
    const float* wrow = W + (long)d * DIM;
    for (int k = 0; k < DIM; ++k) {
        float w = wrow[k];
        #pragma unroll
        for (int j = 0; j < 8; ++j) acc[j] = fmaf(s_in[j][k], w, acc[j]);
    }
    #pragma unroll
    for (int j = 0; j < 8; ++j) {
        int n = node0 + j;
        if (n < N) hs[(long)n * DIM + d] = acc[j] * dinv[n];
    }
}

// ---------- gather aggregation: out[t] = relu(dinv[t]*(sum_{s in N(t)} hs[s] + hs[t]) + b) ----------
// one wave per dst node; float2 per lane (128 dims); atomic-free, coalesced writes
__global__ __launch_bounds__(256) void k_aggregate(
    const int* __restrict__ row_off, const int* __restrict__ csr,
    const float* __restrict__ dinv, const float* __restrict__ hs,
    const float* __restrict__ b, float* __restrict__ out, int N)
{
    int t = blockIdx.x * 4 + (threadIdx.x >> 6);
    int lane = threadIdx.x & 63;
    if (t >= N) return;
    int beg = row_off[t], end = row_off[t + 1];
    const float2* hs2 = (const float2*)hs;
    float2 acc = hs2[(long)t * 64 + lane];          // self-loop term (hs[t], scaled later by dinv[t])
    int k = beg;
    for (; k + 1 < end; k += 2) {
        int s0 = csr[k], s1 = csr[k + 1];
        float2 v0 = hs2[(long)s0 * 64 + lane];
        float2 v1 = hs2[(long)s1 * 64 + lane];
        acc.x += v0.x + v1.x;
        acc.y += v0.y + v1.y;
    }
    if (k < end) {
        int s0 = csr[k];
        float2 v0 = hs2[(long)s0 * 64 + lane];
        acc.x += v0.x; acc.y += v0.y;
    }
    float di = dinv[t];
    float2 bb = ((const float2*)b)[lane];
    float2 o;
    o.x = fmaxf(fmaf(acc.x, di, bb.x), 0.0f);
    o.y = fmaxf(fmaf(acc.y, di, bb.y), 0.0f);
    ((float2*)out)[(long)t * 64 + lane] = o;
}

extern "C" void kernel_launch(void* const* d_in, const int* in_sizes, int n_in,
                              void* d_out, int out_size, void* d_ws, size_t ws_size,
                              hipStream_t stream) {
    const float* x     = (const float*)d_in[0];
    const int*   edge  = (const int*)d_in[1];
    // d_in[2] = batch (unused by the reference output)
    const float* emb   = (const float*)d_in[3];
    const float* lin_W = (const float*)d_in[4];
    const float* lin_b = (const float*)d_in[5];
    const float* g1W   = (const float*)d_in[6];
    const float* g1b   = (const float*)d_in[7];
    const float* g2W   = (const float*)d_in[8];
    const float* g2b   = (const float*)d_in[9];
    float* out = (float*)d_out;

    const int N = in_sizes[0] / NFEAT;
    const int E = in_sizes[1] / 2;
    const int* esrc = edge;
    const int* edst = edge + E;

    // workspace carve-up (re-poisoned to 0xAA before every launch — everything is (re)initialized)
    float* ws0     = (float*)d_ws;                       // N*DIM floats: h / hs scratch
    float* dinv    = ws0 + (size_t)N * DIM;              // N floats
    int*   row_off = (int*)(dinv + N);                   // N+1 ints
    int*   cnt     = row_off + (N + 1);                  // N ints
    int*   cursor  = cnt + N;                            // N ints
    int*   partial = cursor + N;                         // ceil(N/256) ints
    const int nbScan = (N + SCAN_BS - 1) / SCAN_BS;      // 196 for N=50k (must be <= 256)
    int*   csr     = partial + nbScan;                   // E ints

    const int nb8  = (N + 7) / 8;
    const int nbN  = (N + 255) / 256;
    const int nbE  = (E + 255) / 256;
    const int nbAgg = (N + 3) / 4;                       // 4 waves/block, 1 wave/node

    // ---- CSR build (once, shared by both layers) ----
    k_zero_int<<<nbN, 256, 0, stream>>>(cnt, N);
    k_count<<<nbE, 256, 0, stream>>>(edst, cnt, E);
    k_blocksum<<<nbScan, SCAN_BS, 0, stream>>>(cnt, partial, N);
    k_scan_partials<<<1, SCAN_BS, 0, stream>>>(partial, nbScan);
    k_row_off<<<nbScan, SCAN_BS, 0, stream>>>(cnt, partial, row_off, cursor, N, E);
    k_fill<<<nbE, 256, 0, stream>>>(esrc, edst, row_off, cursor, csr, E);
    k_dinv<<<nbN, 256, 0, stream>>>(row_off, dinv, N);

    // ---- h1 = relu(lin(embed ++ fixed)) -> ws0 ----
    k_embed_linear<<<nb8, 128, 0, stream>>>(x, emb, lin_W, lin_b, ws0, N);

    // ---- layer 1: hs -> ws0 (in place), aggregate -> d_out ----
    k_gcn_gemm<<<nb8, 128, 0, stream>>>(ws0, g1W, dinv, ws0, N);
    k_aggregate<<<nbAgg, 256, 0, stream>>>(row_off, csr, dinv, ws0, g1b, out, N);

    // ---- layer 2: hs -> ws0, aggregate -> d_out (read ws0, write out; no alias) ----
    k_gcn_gemm<<<nb8, 128, 0, stream>>>(out, g2W, dinv, ws0, N);
    k_aggregate<<<nbAgg, 256, 0, stream>>>(row_off, csr, dinv, ws0, g2b, out, N);
}

// Round 3
// 406.022 us; speedup vs baseline: 4.0857x; 1.2066x over previous
//
#include <hip/hip_runtime.h>

#define NFEAT 78
#define NTYPES 44
#define NFIX 34
#define DIM 128
#define LIN_K 162   // DIM + NFIX
#define SA_STRIDE 164  // LIN_K padded to mult of 4 for float4 LDS writes

// ================= transpose W matrices (once per launch) =================
// lin_W [128][162] -> linWt [162][128]; g1W/g2W [128][128] -> [128][128]
__global__ __launch_bounds__(256) void k_transpose_all(
    const float* __restrict__ w0, const float* __restrict__ w1,
    const float* __restrict__ w2, float* __restrict__ t0,
    float* __restrict__ t1, float* __restrict__ t2)
{
    int sel = blockIdx.y;
    const float* src = sel == 0 ? w0 : (sel == 1 ? w1 : w2);
    float*       dst = sel == 0 ? t0 : (sel == 1 ? t1 : t2);
    const int R = 128;
    const int C = (sel == 0) ? LIN_K : DIM;
    int tc = (C + 31) / 32;
    int bx = blockIdx.x % tc, by = blockIdx.x / tc;
    if (by >= (R + 31) / 32) return;
    __shared__ float tile[32][33];
    int ty = threadIdx.x >> 5, tx = threadIdx.x & 31;
    int c0 = bx * 32, r0 = by * 32;
    #pragma unroll
    for (int j = 0; j < 32; j += 8) {
        int r = r0 + ty + j, c = c0 + tx;
        tile[ty + j][tx] = (r < R && c < C) ? src[r * C + c] : 0.0f;
    }
    __syncthreads();
    #pragma unroll
    for (int j = 0; j < 32; j += 8) {
        int c = c0 + ty + j, r = r0 + tx;
        if (c < C && r < R) dst[c * R + r] = tile[tx][ty + j];
    }
}

// ================= CSR build =================
__global__ void k_zero(int* __restrict__ cnt, int* __restrict__ gbase, int N) {
    int i = blockIdx.x * 256 + threadIdx.x;
    if (i < N) cnt[i] = 0;
    if (i == 0) *gbase = 0;
}
__global__ void k_count(const int* __restrict__ dst, int* __restrict__ cnt, int E) {
    int e = blockIdx.x * 256 + threadIdx.x;
    if (e < E) atomicAdd(&cnt[dst[e]], 1);
}
// block-local exclusive scan + atomic global base; also dinv + cursor init
__global__ __launch_bounds__(256) void k_base(
    const int* __restrict__ cnt, int* __restrict__ gbase,
    int* __restrict__ row_off, int* __restrict__ cursor,
    float* __restrict__ dinv, int N)
{
    __shared__ int s[256];
    __shared__ int base;
    int t = threadIdx.x, i = blockIdx.x * 256 + t;
    int c = (i < N) ? cnt[i] : 0;
    s[t] = c;
    __syncthreads();
    for (int off = 1; off < 256; off <<= 1) {
        int u = (t >= off) ? s[t - off] : 0;
        __syncthreads();
        s[t] += u;
        __syncthreads();
    }
    if (t == 255) base = atomicAdd(gbase, s[255]);
    __syncthreads();
    if (i < N) {
        row_off[i] = base + s[t] - c;   // exclusive within block + global base
        cursor[i] = 0;
        dinv[i] = rsqrtf((float)(c + 1));  // + self-loop
    }
}
__global__ void k_fill(const int* __restrict__ src, const int* __restrict__ dst,
                       const int* __restrict__ row_off, int* __restrict__ cursor,
                       int* __restrict__ csr, int E)
{
    int e = blockIdx.x * 256 + threadIdx.x;
    if (e < E) {
        int t = dst[e];
        int pos = atomicAdd(&cursor[t], 1);
        csr[row_off[t] + pos] = src[e];
    }
}

// ================= embed + linear: h = relu(concat(emb[argmax], xfix) @ linW^T + b) =================
// 256 threads, 64-node tile; thread = (tx: 4 d-dims, ty: 8 nodes); Wt pre-transposed [162][128]
__global__ __launch_bounds__(256) void k_embed_linear(
    const float* __restrict__ x, const float* __restrict__ emb,
    const float* __restrict__ Wt, const float* __restrict__ b,
    float* __restrict__ h, int N)
{
    __shared__ float s_a[64][SA_STRIDE];
    __shared__ int s_idx[64];
    const int tid = threadIdx.x;
    const int node0 = blockIdx.x * 64;

    // argmax over atom-type block, one thread per node
    if (tid < 64) {
        int n = node0 + tid;
        int bi = 0;
        if (n < N) {
            const float* xr = x + (long)n * NFEAT;
            float best = xr[0];
            for (int k = 1; k < NTYPES; ++k) {
                float v = xr[k];
                if (v > best) { best = v; bi = k; }   // strict >: first max (jnp.argmax)
            }
        }
        s_idx[tid] = bi;
    }
    __syncthreads();
    // fixed features -> cols 128..161
    for (int q = tid; q < 64 * NFIX; q += 256) {
        int m = q / NFIX, c = q - m * NFIX;
        int n = node0 + m;
        s_a[m][DIM + c] = (n < N) ? x[(long)n * NFEAT + NTYPES + c] : 0.0f;
    }
    __syncthreads();
    // embedding rows -> cols 0..127 (float4)
    const float4* emb4 = (const float4*)emb;
    for (int q = tid; q < 64 * 32; q += 256) {
        int m = q >> 5, c4 = q & 31;
        *((float4*)&s_a[m][c4 * 4]) = emb4[s_idx[m] * 32 + c4];
    }
    __syncthreads();

    const int tx = tid & 31;       // 4 d-dims: 4*tx..4*tx+3
    const int m0 = (tid >> 5) * 8; // 8 nodes
    const float4* Wt4 = (const float4*)Wt;
    float4 bb = ((const float4*)b)[tx];
    float4 acc[8];
    #pragma unroll
    for (int j = 0; j < 8; ++j) acc[j] = bb;
    #pragma unroll 2
    for (int k = 0; k < LIN_K; ++k) {
        float4 w = Wt4[k * 32 + tx];
        #pragma unroll
        for (int j = 0; j < 8; ++j) {
            float a = s_a[m0 + j][k];
            acc[j].x = fmaf(a, w.x, acc[j].x);
            acc[j].y = fmaf(a, w.y, acc[j].y);
            acc[j].z = fmaf(a, w.z, acc[j].z);
            acc[j].w = fmaf(a, w.w, acc[j].w);
        }
    }
    #pragma unroll
    for (int j = 0; j < 8; ++j) {
        int n = node0 + m0 + j;
        if (n < N) {
            float4 o;
            o.x = fmaxf(acc[j].x, 0.0f); o.y = fmaxf(acc[j].y, 0.0f);
            o.z = fmaxf(acc[j].z, 0.0f); o.w = fmaxf(acc[j].w, 0.0f);
            ((float4*)h)[(long)n * 32 + tx] = o;
        }
    }
}

// ================= GCN linear: hs = (hin @ W^T) * dinv[n] =================
// same tiling; Wt pre-transposed [128][128]; hin may alias hs (block stages own rows first)
__global__ __launch_bounds__(256) void k_gcn_gemm(
    const float* __restrict__ hin, const float* __restrict__ Wt,
    const float* __restrict__ dinv, float* __restrict__ hs, int N)
{
    __shared__ float s_a[64][DIM];
    const int tid = threadIdx.x;
    const int node0 = blockIdx.x * 64;

    const float4* hin4 = (const float4*)hin;
    for (int q = tid; q < 64 * 32; q += 256) {
        int m = q >> 5, c4 = q & 31;
        int n = node0 + m;
        float4 v = (n < N) ? hin4[(long)n * 32 + c4] : make_float4(0, 0, 0, 0);
        *((float4*)&s_a[m][c4 * 4]) = v;
    }
    __syncthreads();

    const int tx = tid & 31;
    const int m0 = (tid >> 5) * 8;
    const float4* Wt4 = (const float4*)Wt;
    float4 acc[8];
    #pragma unroll
    for (int j = 0; j < 8; ++j) acc[j] = make_float4(0, 0, 0, 0);
    #pragma unroll 2
    for (int k = 0; k < DIM; ++k) {
        float4 w = Wt4[k * 32 + tx];
        #pragma unroll
        for (int j = 0; j < 8; ++j) {
            float a = s_a[m0 + j][k];
            acc[j].x = fmaf(a, w.x, acc[j].x);
            acc[j].y = fmaf(a, w.y, acc[j].y);
            acc[j].z = fmaf(a, w.z, acc[j].z);
            acc[j].w = fmaf(a, w.w, acc[j].w);
        }
    }
    #pragma unroll
    for (int j = 0; j < 8; ++j) {
        int n = node0 + m0 + j;
        if (n < N) {
            float di = dinv[n];
            float4 o;
            o.x = acc[j].x * di; o.y = acc[j].y * di;
            o.z = acc[j].z * di; o.w = acc[j].w * di;
            ((float4*)hs)[(long)n * 32 + tx] = o;
        }
    }
}

// ================= gather aggregation =================
// out[t] = relu(dinv[t]*(sum_{s in N(t)} hs[s] + hs[t]) + b); half-wave (32 lanes x float4) per node
__global__ __launch_bounds__(256) void k_aggregate(
    const int* __restrict__ row_off, const int* __restrict__ cnt,
    const int* __restrict__ csr, const float* __restrict__ dinv,
    const float* __restrict__ hs, const float* __restrict__ b,
    float* __restrict__ out, int N)
{
    int t = blockIdx.x * 8 + (threadIdx.x >> 5);
    int l = threadIdx.x & 31;
    if (t >= N) return;
    int beg = row_off[t], len = cnt[t];
    const float4* hs4 = (const float4*)hs;
    float4 acc = hs4[(long)t * 32 + l];   // self-loop term
    int k = 0;
    for (; k + 1 < len; k += 2) {
        int s0 = csr[beg + k], s1 = csr[beg + k + 1];
        float4 v0 = hs4[(long)s0 * 32 + l];
        float4 v1 = hs4[(long)s1 * 32 + l];
        acc.x += v0.x + v1.x; acc.y += v0.y + v1.y;
        acc.z += v0.z + v1.z; acc.w += v0.w + v1.w;
    }
    if (k < len) {
        int s0 = csr[beg + k];
        float4 v0 = hs4[(long)s0 * 32 + l];
        acc.x += v0.x; acc.y += v0.y; acc.z += v0.z; acc.w += v0.w;
    }
    float di = dinv[t];
    float4 bb = ((const float4*)b)[l];
    float4 o;
    o.x = fmaxf(fmaf(acc.x, di, bb.x), 0.0f);
    o.y = fmaxf(fmaf(acc.y, di, bb.y), 0.0f);
    o.z = fmaxf(fmaf(acc.z, di, bb.z), 0.0f);
    o.w = fmaxf(fmaf(acc.w, di, bb.w), 0.0f);
    ((float4*)out)[(long)t * 32 + l] = o;
}

extern "C" void kernel_launch(void* const* d_in, const int* in_sizes, int n_in,
                              void* d_out, int out_size, void* d_ws, size_t ws_size,
                              hipStream_t stream) {
    const float* x     = (const float*)d_in[0];
    const int*   edge  = (const int*)d_in[1];
    // d_in[2] = batch (unused)
    const float* emb   = (const float*)d_in[3];
    const float* lin_W = (const float*)d_in[4];
    const float* lin_b = (const float*)d_in[5];
    const float* g1W   = (const float*)d_in[6];
    const float* g1b   = (const float*)d_in[7];
    const float* g2W   = (const float*)d_in[8];
    const float* g2b   = (const float*)d_in[9];
    float* out = (float*)d_out;

    const int N = in_sizes[0] / NFEAT;
    const int E = in_sizes[1] / 2;
    const int* esrc = edge;
    const int* edst = edge + E;

    // workspace carve-up (everything initialized every launch; ws re-poisoned)
    float* ws0     = (float*)d_ws;                       // N*DIM floats
    float* dinv    = ws0 + (size_t)N * DIM;              // N
    int*   row_off = (int*)(dinv + N);                   // N
    int*   cnt     = row_off + N;                        // N
    int*   cursor  = cnt + N;                            // N
    int*   gbase   = cursor + N;                         // 4 (padded)
    int*   csr     = gbase + 4;                          // E
    float* linWt   = (float*)(csr + E);                  // 162*128
    float* g1Wt    = linWt + LIN_K * DIM;                // 128*128
    float* g2Wt    = g1Wt + DIM * DIM;                   // 128*128

    const int nb64 = (N + 63) / 64;
    const int nbN  = (N + 255) / 256;
    const int nbE  = (E + 255) / 256;
    const int nbAgg = (N + 7) / 8;

    // transposed weights (Wt[k][d]) for vectorized B-loads
    k_transpose_all<<<dim3(24, 3), 256, 0, stream>>>(lin_W, g1W, g2W, linWt, g1Wt, g2Wt);

    // CSR build
    k_zero<<<nbN, 256, 0, stream>>>(cnt, gbase, N);
    k_count<<<nbE, 256, 0, stream>>>(edst, cnt, E);
    k_base<<<nbN, 256, 0, stream>>>(cnt, gbase, row_off, cursor, dinv, N);
    k_fill<<<nbE, 256, 0, stream>>>(esrc, edst, row_off, cursor, csr, E);

    // h1 = relu(lin(embed ++ fixed)) -> ws0
    k_embed_linear<<<nb64, 256, 0, stream>>>(x, emb, linWt, lin_b, ws0, N);

    // layer 1: hs -> ws0 (in place), aggregate -> d_out
    k_gcn_gemm<<<nb64, 256, 0, stream>>>(ws0, g1Wt, dinv, ws0, N);
    k_aggregate<<<nbAgg, 256, 0, stream>>>(row_off, cnt, csr, dinv, ws0, g1b, out, N);

    // layer 2: hs -> ws0, aggregate -> d_out
    k_gcn_gemm<<<nb64, 256, 0, stream>>>(out, g2Wt, dinv, ws0, N);
    k_aggregate<<<nbAgg, 256, 0, stream>>>(row_off, cnt, csr, dinv, ws0, g2b, out, N);
}

// Round 4
// 385.413 us; speedup vs baseline: 4.3042x; 1.0535x over previous
//
#include <hip/hip_runtime.h>

#define NFEAT 78
#define NTYPES 44
#define NFIX 34
#define DIM 128
#define LIN_K 162   // DIM + NFIX
#define FIXP 36     // NFIX padded

// ================= transpose W matrices (once per launch) =================
// lin_W [128][162] -> linWt [162][128]; g1W/g2W [128][128] -> [128][128]
__global__ __launch_bounds__(256) void k_transpose_all(
    const float* __restrict__ w0, const float* __restrict__ w1,
    const float* __restrict__ w2, float* __restrict__ t0,
    float* __restrict__ t1, float* __restrict__ t2)
{
    int sel = blockIdx.y;
    const float* src = sel == 0 ? w0 : (sel == 1 ? w1 : w2);
    float*       dst = sel == 0 ? t0 : (sel == 1 ? t1 : t2);
    const int R = 128;
    const int C = (sel == 0) ? LIN_K : DIM;
    int tc = (C + 31) / 32;
    int bx = blockIdx.x % tc, by = blockIdx.x / tc;
    if (by >= (R + 31) / 32) return;
    __shared__ float tile[32][33];
    int ty = threadIdx.x >> 5, tx = threadIdx.x & 31;
    int c0 = bx * 32, r0 = by * 32;
    #pragma unroll
    for (int j = 0; j < 32; j += 8) {
        int r = r0 + ty + j, c = c0 + tx;
        tile[ty + j][tx] = (r < R && c < C) ? src[r * C + c] : 0.0f;
    }
    __syncthreads();
    #pragma unroll
    for (int j = 0; j < 32; j += 8) {
        int c = c0 + ty + j, r = r0 + tx;
        if (c < C && r < R) dst[c * R + r] = tile[tx][ty + j];
    }
}

// ================= embWb[t][d] = b[d] + sum_k emb[t][k] * linWt[k][d]  (44x128, K=128) =================
__global__ __launch_bounds__(128) void k_embW(
    const float* __restrict__ emb, const float* __restrict__ linWt,
    const float* __restrict__ b, float* __restrict__ embWb)
{
    __shared__ float s_e[DIM];
    const int t = blockIdx.x;       // 0..43
    const int d = threadIdx.x;      // 0..127
    s_e[d] = emb[t * DIM + d];
    __syncthreads();
    float acc = b[d];
    #pragma unroll 4
    for (int k = 0; k < DIM; ++k)
        acc = fmaf(s_e[k], linWt[k * DIM + d], acc);
    embWb[t * DIM + d] = acc;
}

// ================= CSR build =================
__global__ void k_zero(int* __restrict__ cnt, int* __restrict__ gbase, int N) {
    int i = blockIdx.x * 256 + threadIdx.x;
    if (i < N) cnt[i] = 0;
    if (i == 0) *gbase = 0;
}
__global__ void k_count(const int* __restrict__ dst, int* __restrict__ cnt, int E) {
    int e = blockIdx.x * 256 + threadIdx.x;
    if (e < E) atomicAdd(&cnt[dst[e]], 1);
}
// block-local exclusive scan + atomic global base; also dinv + cursor init
__global__ __launch_bounds__(256) void k_base(
    const int* __restrict__ cnt, int* __restrict__ gbase,
    int* __restrict__ row_off, int* __restrict__ cursor,
    float* __restrict__ dinv, int N)
{
    __shared__ int s[256];
    __shared__ int base;
    int t = threadIdx.x, i = blockIdx.x * 256 + t;
    int c = (i < N) ? cnt[i] : 0;
    s[t] = c;
    __syncthreads();
    for (int off = 1; off < 256; off <<= 1) {
        int u = (t >= off) ? s[t - off] : 0;
        __syncthreads();
        s[t] += u;
        __syncthreads();
    }
    if (t == 255) base = atomicAdd(gbase, s[255]);
    __syncthreads();
    if (i < N) {
        row_off[i] = base + s[t] - c;   // exclusive within block + global base
        cursor[i] = 0;
        dinv[i] = rsqrtf((float)(c + 1));  // + self-loop
    }
}
__global__ void k_fill(const int* __restrict__ src, const int* __restrict__ dst,
                       const int* __restrict__ row_off, int* __restrict__ cursor,
                       int* __restrict__ csr, int E)
{
    int e = blockIdx.x * 256 + threadIdx.x;
    if (e < E) {
        int t = dst[e];
        int pos = atomicAdd(&cursor[t], 1);
        csr[row_off[t] + pos] = src[e];
    }
}

// ================= embed + linear (K=34): h = relu(embWb[argmax] + xfix @ W2t) =================
// 64-node tile, 256 threads; thread = (tx: 4 dims float4, ty: 8 nodes); LDS ~9.5 KB
__global__ __launch_bounds__(256) void k_embed_linear(
    const float* __restrict__ x, const float* __restrict__ embWb,
    const float* __restrict__ W2t, float* __restrict__ h, int N)
{
    __shared__ float s_fix[64][FIXP];
    __shared__ int s_idx[64];
    const int tid = threadIdx.x;
    const int node0 = blockIdx.x * 64;

    // argmax over atom-type block, one thread per node
    if (tid < 64) {
        int n = node0 + tid;
        int bi = 0;
        if (n < N) {
            const float* xr = x + (long)n * NFEAT;
            float best = xr[0];
            for (int k = 1; k < NTYPES; ++k) {
                float v = xr[k];
                if (v > best) { best = v; bi = k; }   // strict >: first max (jnp.argmax)
            }
        }
        s_idx[tid] = bi;
    }
    // fixed features -> s_fix
    for (int q = tid; q < 64 * NFIX; q += 256) {
        int m = q / NFIX, c = q - m * NFIX;
        int n = node0 + m;
        s_fix[m][c] = (n < N) ? x[(long)n * NFEAT + NTYPES + c] : 0.0f;
    }
    __syncthreads();

    const int tx = tid & 31;       // 4 d-dims: 4*tx..4*tx+3
    const int m0 = (tid >> 5) * 8; // 8 nodes
    const float4* Wt4 = (const float4*)W2t;
    const float4* eb4 = (const float4*)embWb;
    float4 acc[8];
    #pragma unroll
    for (int j = 0; j < 8; ++j) acc[j] = eb4[s_idx[m0 + j] * 32 + tx];  // emb@W1 + b, gathered
    #pragma unroll 2
    for (int k = 0; k < NFIX; ++k) {
        float4 w = Wt4[k * 32 + tx];
        #pragma unroll
        for (int j = 0; j < 8; ++j) {
            float a = s_fix[m0 + j][k];
            acc[j].x = fmaf(a, w.x, acc[j].x);
            acc[j].y = fmaf(a, w.y, acc[j].y);
            acc[j].z = fmaf(a, w.z, acc[j].z);
            acc[j].w = fmaf(a, w.w, acc[j].w);
        }
    }
    #pragma unroll
    for (int j = 0; j < 8; ++j) {
        int n = node0 + m0 + j;
        if (n < N) {
            float4 o;
            o.x = fmaxf(acc[j].x, 0.0f); o.y = fmaxf(acc[j].y, 0.0f);
            o.z = fmaxf(acc[j].z, 0.0f); o.w = fmaxf(acc[j].w, 0.0f);
            ((float4*)h)[(long)n * 32 + tx] = o;
        }
    }
}

// ================= GCN linear: hs = (hin @ W^T) * dinv[n] =================
// 64-node tile; Wt pre-transposed [128][128]; hin may alias hs (block stages own rows first)
__global__ __launch_bounds__(256) void k_gcn_gemm(
    const float* __restrict__ hin, const float* __restrict__ Wt,
    const float* __restrict__ dinv, float* __restrict__ hs, int N)
{
    __shared__ float s_a[64][DIM];
    const int tid = threadIdx.x;
    const int node0 = blockIdx.x * 64;

    const float4* hin4 = (const float4*)hin;
    for (int q = tid; q < 64 * 32; q += 256) {
        int m = q >> 5, c4 = q & 31;
        int n = node0 + m;
        float4 v = (n < N) ? hin4[(long)n * 32 + c4] : make_float4(0, 0, 0, 0);
        *((float4*)&s_a[m][c4 * 4]) = v;
    }
    __syncthreads();

    const int tx = tid & 31;
    const int m0 = (tid >> 5) * 8;
    const float4* Wt4 = (const float4*)Wt;
    float4 acc[8];
    #pragma unroll
    for (int j = 0; j < 8; ++j) acc[j] = make_float4(0, 0, 0, 0);
    #pragma unroll 2
    for (int k = 0; k < DIM; ++k) {
        float4 w = Wt4[k * 32 + tx];
        #pragma unroll
        for (int j = 0; j < 8; ++j) {
            float a = s_a[m0 + j][k];
            acc[j].x = fmaf(a, w.x, acc[j].x);
            acc[j].y = fmaf(a, w.y, acc[j].y);
            acc[j].z = fmaf(a, w.z, acc[j].z);
            acc[j].w = fmaf(a, w.w, acc[j].w);
        }
    }
    #pragma unroll
    for (int j = 0; j < 8; ++j) {
        int n = node0 + m0 + j;
        if (n < N) {
            float di = dinv[n];
            float4 o;
            o.x = acc[j].x * di; o.y = acc[j].y * di;
            o.z = acc[j].z * di; o.w = acc[j].w * di;
            ((float4*)hs)[(long)n * 32 + tx] = o;
        }
    }
}

// ================= gather aggregation =================
// out[t] = relu(dinv[t]*(sum_{s in N(t)} hs[s] + hs[t]) + b); half-wave (32 lanes x float4) per node
__global__ __launch_bounds__(256) void k_aggregate(
    const int* __restrict__ row_off, const int* __restrict__ cnt,
    const int* __restrict__ csr, const float* __restrict__ dinv,
    const float* __restrict__ hs, const float* __restrict__ b,
    float* __restrict__ out, int N)
{
    int t = blockIdx.x * 8 + (threadIdx.x >> 5);
    int l = threadIdx.x & 31;
    if (t >= N) return;
    int beg = row_off[t], len = cnt[t];
    const float4* hs4 = (const float4*)hs;
    float4 acc = hs4[(long)t * 32 + l];   // self-loop term
    int k = 0;
    for (; k + 3 < len; k += 4) {
        int s0 = csr[beg + k],     s1 = csr[beg + k + 1];
        int s2 = csr[beg + k + 2], s3 = csr[beg + k + 3];
        float4 v0 = hs4[(long)s0 * 32 + l];
        float4 v1 = hs4[(long)s1 * 32 + l];
        float4 v2 = hs4[(long)s2 * 32 + l];
        float4 v3 = hs4[(long)s3 * 32 + l];
        acc.x += (v0.x + v1.x) + (v2.x + v3.x);
        acc.y += (v0.y + v1.y) + (v2.y + v3.y);
        acc.z += (v0.z + v1.z) + (v2.z + v3.z);
        acc.w += (v0.w + v1.w) + (v2.w + v3.w);
    }
    for (; k < len; ++k) {
        int s0 = csr[beg + k];
        float4 v0 = hs4[(long)s0 * 32 + l];
        acc.x += v0.x; acc.y += v0.y; acc.z += v0.z; acc.w += v0.w;
    }
    float di = dinv[t];
    float4 bb = ((const float4*)b)[l];
    float4 o;
    o.x = fmaxf(fmaf(acc.x, di, bb.x), 0.0f);
    o.y = fmaxf(fmaf(acc.y, di, bb.y), 0.0f);
    o.z = fmaxf(fmaf(acc.z, di, bb.z), 0.0f);
    o.w = fmaxf(fmaf(acc.w, di, bb.w), 0.0f);
    ((float4*)out)[(long)t * 32 + l] = o;
}

extern "C" void kernel_launch(void* const* d_in, const int* in_sizes, int n_in,
                              void* d_out, int out_size, void* d_ws, size_t ws_size,
                              hipStream_t stream) {
    const float* x     = (const float*)d_in[0];
    const int*   edge  = (const int*)d_in[1];
    // d_in[2] = batch (unused)
    const float* emb   = (const float*)d_in[3];
    const float* lin_W = (const float*)d_in[4];
    const float* lin_b = (const float*)d_in[5];
    const float* g1W   = (const float*)d_in[6];
    const float* g1b   = (const float*)d_in[7];
    const float* g2W   = (const float*)d_in[8];
    const float* g2b   = (const float*)d_in[9];
    float* out = (float*)d_out;

    const int N = in_sizes[0] / NFEAT;
    const int E = in_sizes[1] / 2;
    const int* esrc = edge;
    const int* edst = edge + E;

    // workspace carve-up (everything initialized every launch; ws re-poisoned)
    float* ws0     = (float*)d_ws;                       // N*DIM floats
    float* dinv    = ws0 + (size_t)N * DIM;              // N
    int*   row_off = (int*)(dinv + N);                   // N
    int*   cnt     = row_off + N;                        // N
    int*   cursor  = cnt + N;                            // N
    int*   gbase   = cursor + N;                         // 4 (padded)
    int*   csr     = gbase + 4;                          // E
    float* linWt   = (float*)(csr + E);                  // 162*128
    float* g1Wt    = linWt + LIN_K * DIM;                // 128*128
    float* g2Wt    = g1Wt + DIM * DIM;                   // 128*128
    float* embWb   = g2Wt + DIM * DIM;                   // 44*128

    const int nb64 = (N + 63) / 64;
    const int nbN  = (N + 255) / 256;
    const int nbE  = (E + 255) / 256;
    const int nbAgg = (N + 7) / 8;

    // transposed weights (Wt[k][d]) for vectorized B-loads
    k_transpose_all<<<dim3(24, 3), 256, 0, stream>>>(lin_W, g1W, g2W, linWt, g1Wt, g2Wt);
    // embWb = emb @ linWt[:128] + b  (44x128)
    k_embW<<<NTYPES, 128, 0, stream>>>(emb, linWt, lin_b, embWb);

    // CSR build
    k_zero<<<nbN, 256, 0, stream>>>(cnt, gbase, N);
    k_count<<<nbE, 256, 0, stream>>>(edst, cnt, E);
    k_base<<<nbN, 256, 0, stream>>>(cnt, gbase, row_off, cursor, dinv, N);
    k_fill<<<nbE, 256, 0, stream>>>(esrc, edst, row_off, cursor, csr, E);

    // h1 = relu(embWb[idx] + xfix @ W2t) -> ws0   (W2t = rows 128..161 of linWt)
    k_embed_linear<<<nb64, 256, 0, stream>>>(x, embWb, linWt + DIM * DIM, ws0, N);

    // layer 1: hs -> ws0 (in place), aggregate -> d_out
    k_gcn_gemm<<<nb64, 256, 0, stream>>>(ws0, g1Wt, dinv, ws0, N);
    k_aggregate<<<nbAgg, 256, 0, stream>>>(row_off, cnt, csr, dinv, ws0, g1b, out, N);

    // layer 2: hs -> ws0, aggregate -> d_out
    k_gcn_gemm<<<nb64, 256, 0, stream>>>(out, g2Wt, dinv, ws0, N);
    k_aggregate<<<nbAgg, 256, 0, stream>>>(row_off, cnt, csr, dinv, ws0, g2b, out, N);
}

// Round 5
// 339.816 us; speedup vs baseline: 4.8817x; 1.1342x over previous
//
#include <hip/hip_runtime.h>

#define NFEAT 78
#define NTYPES 44
#define NFIX 34
#define DIM 128
#define LIN_K 162   // DIM + NFIX
#define FIXP 36     // NFIX padded
#define APAD 132    // DIM + 4: LDS row pad (keeps float4 alignment, breaks pow2 stride)

typedef unsigned int uint32;

// ---------- bf16 helpers (messages stored bf16, accumulated fp32) ----------
__device__ __forceinline__ unsigned short f2bf(float f) {
    uint32 u = __float_as_uint(f);
    u += 0x7FFFu + ((u >> 16) & 1u);      // round-to-nearest-even
    return (unsigned short)(u >> 16);
}
__device__ __forceinline__ void bf_acc(uint4 v, float4& A, float4& B) {
    A.x += __uint_as_float(v.x << 16); A.y += __uint_as_float(v.x & 0xFFFF0000u);
    A.z += __uint_as_float(v.y << 16); A.w += __uint_as_float(v.y & 0xFFFF0000u);
    B.x += __uint_as_float(v.z << 16); B.y += __uint_as_float(v.z & 0xFFFF0000u);
    B.z += __uint_as_float(v.w << 16); B.w += __uint_as_float(v.w & 0xFFFF0000u);
}

// ================= transpose W matrices (once per launch) =================
__global__ __launch_bounds__(256) void k_transpose_all(
    const float* __restrict__ w0, const float* __restrict__ w1,
    const float* __restrict__ w2, float* __restrict__ t0,
    float* __restrict__ t1, float* __restrict__ t2)
{
    int sel = blockIdx.y;
    const float* src = sel == 0 ? w0 : (sel == 1 ? w1 : w2);
    float*       dst = sel == 0 ? t0 : (sel == 1 ? t1 : t2);
    const int R = 128;
    const int C = (sel == 0) ? LIN_K : DIM;
    int tc = (C + 31) / 32;
    int bx = blockIdx.x % tc, by = blockIdx.x / tc;
    if (by >= (R + 31) / 32) return;
    __shared__ float tile[32][33];
    int ty = threadIdx.x >> 5, tx = threadIdx.x & 31;
    int c0 = bx * 32, r0 = by * 32;
    #pragma unroll
    for (int j = 0; j < 32; j += 8) {
        int r = r0 + ty + j, c = c0 + tx;
        tile[ty + j][tx] = (r < R && c < C) ? src[r * C + c] : 0.0f;
    }
    __syncthreads();
    #pragma unroll
    for (int j = 0; j < 32; j += 8) {
        int c = c0 + ty + j, r = r0 + tx;
        if (c < C && r < R) dst[c * R + r] = tile[tx][ty + j];
    }
}

// ================= embWb[t][d] = b[d] + sum_k emb[t][k]*linWt[k][d]  (44x128) =================
__global__ __launch_bounds__(128) void k_embW(
    const float* __restrict__ emb, const float* __restrict__ linWt,
    const float* __restrict__ b, float* __restrict__ embWb)
{
    __shared__ float s_e[DIM];
    const int t = blockIdx.x;
    const int d = threadIdx.x;
    s_e[d] = emb[t * DIM + d];
    __syncthreads();
    float acc = b[d];
    #pragma unroll 4
    for (int k = 0; k < DIM; ++k)
        acc = fmaf(s_e[k], linWt[k * DIM + d], acc);
    embWb[t * DIM + d] = acc;
}

// ================= CSR build =================
__global__ void k_zero(int* __restrict__ cnt, int* __restrict__ gbase, int N) {
    int i = blockIdx.x * 256 + threadIdx.x;
    if (i < N) cnt[i] = 0;
    if (i == 0) *gbase = 0;
}
__global__ void k_count(const int* __restrict__ dst, int* __restrict__ cnt, int E) {
    int e = blockIdx.x * 256 + threadIdx.x;
    if (e < E) atomicAdd(&cnt[dst[e]], 1);
}
__global__ __launch_bounds__(256) void k_base(
    const int* __restrict__ cnt, int* __restrict__ gbase,
    int* __restrict__ row_off, int* __restrict__ cursor,
    float* __restrict__ dinv, int N)
{
    __shared__ int s[256];
    __shared__ int base;
    int t = threadIdx.x, i = blockIdx.x * 256 + t;
    int c = (i < N) ? cnt[i] : 0;
    s[t] = c;
    __syncthreads();
    for (int off = 1; off < 256; off <<= 1) {
        int u = (t >= off) ? s[t - off] : 0;
        __syncthreads();
        s[t] += u;
        __syncthreads();
    }
    if (t == 255) base = atomicAdd(gbase, s[255]);
    __syncthreads();
    if (i < N) {
        row_off[i] = base + s[t] - c;
        cursor[i] = 0;
        dinv[i] = rsqrtf((float)(c + 1));   // + self-loop
    }
}
__global__ void k_fill(const int* __restrict__ src, const int* __restrict__ dst,
                       const int* __restrict__ row_off, int* __restrict__ cursor,
                       int* __restrict__ csr, int E)
{
    int e = blockIdx.x * 256 + threadIdx.x;
    if (e < E) {
        int t = dst[e];
        int pos = atomicAdd(&cursor[t], 1);
        csr[row_off[t] + pos] = src[e];
    }
}

// ================= fused A: h1 = relu(embWb[argmax] + xfix@W2t); hs1 = bf16((h1@g1W^T)*dinv) =================
__global__ __launch_bounds__(256) void k_embed_gemm1(
    const float* __restrict__ x, const float* __restrict__ embWb,
    const float* __restrict__ W2t, const float* __restrict__ Wt,
    const float* __restrict__ dinv, unsigned short* __restrict__ hs1, int N)
{
    __shared__ float s_fix[64][FIXP];
    __shared__ int   s_idx[64];
    __shared__ float s_h[64][APAD];
    const int tid = threadIdx.x;
    const int node0 = blockIdx.x * 64;

    if (tid < 64) {
        int n = node0 + tid;
        int bi = 0;
        if (n < N) {
            const float* xr = x + (long)n * NFEAT;
            float best = xr[0];
            for (int k = 1; k < NTYPES; ++k) {
                float v = xr[k];
                if (v > best) { best = v; bi = k; }   // strict >: first max (jnp.argmax)
            }
        }
        s_idx[tid] = bi;
    }
    for (int q = tid; q < 64 * NFIX; q += 256) {
        int m = q / NFIX, c = q - m * NFIX;
        int n = node0 + m;
        s_fix[m][c] = (n < N) ? x[(long)n * NFEAT + NTYPES + c] : 0.0f;
    }
    __syncthreads();

    const int tx = tid & 31;       // 4 dims: 4tx..4tx+3
    const int m0 = (tid >> 5) * 8; // 8 nodes
    const float4* W2t4 = (const float4*)W2t;
    const float4* eb4  = (const float4*)embWb;
    float4 acc[8];
    #pragma unroll
    for (int j = 0; j < 8; ++j) acc[j] = eb4[s_idx[m0 + j] * 32 + tx];
    #pragma unroll 2
    for (int k = 0; k < NFIX; ++k) {
        float4 w = W2t4[k * 32 + tx];
        #pragma unroll
        for (int j = 0; j < 8; ++j) {
            float a = s_fix[m0 + j][k];
            acc[j].x = fmaf(a, w.x, acc[j].x);
            acc[j].y = fmaf(a, w.y, acc[j].y);
            acc[j].z = fmaf(a, w.z, acc[j].z);
            acc[j].w = fmaf(a, w.w, acc[j].w);
        }
    }
    #pragma unroll
    for (int j = 0; j < 8; ++j) {
        float4 o;
        o.x = fmaxf(acc[j].x, 0.0f); o.y = fmaxf(acc[j].y, 0.0f);
        o.z = fmaxf(acc[j].z, 0.0f); o.w = fmaxf(acc[j].w, 0.0f);
        *((float4*)&s_h[m0 + j][4 * tx]) = o;
    }
    __syncthreads();

    // gemm1 from LDS
    const float4* Wt4 = (const float4*)Wt;
    float4 c[8];
    #pragma unroll
    for (int j = 0; j < 8; ++j) c[j] = make_float4(0, 0, 0, 0);
    #pragma unroll 2
    for (int k = 0; k < DIM; ++k) {
        float4 w = Wt4[k * 32 + tx];
        #pragma unroll
        for (int j = 0; j < 8; ++j) {
            float a = s_h[m0 + j][k];
            c[j].x = fmaf(a, w.x, c[j].x);
            c[j].y = fmaf(a, w.y, c[j].y);
            c[j].z = fmaf(a, w.z, c[j].z);
            c[j].w = fmaf(a, w.w, c[j].w);
        }
    }
    #pragma unroll
    for (int j = 0; j < 8; ++j) {
        int n = node0 + m0 + j;
        if (n < N) {
            float di = dinv[n];
            ushort4 o;
            o.x = f2bf(c[j].x * di); o.y = f2bf(c[j].y * di);
            o.z = f2bf(c[j].z * di); o.w = f2bf(c[j].w * di);
            ((ushort4*)hs1)[(long)n * 32 + tx] = o;
        }
    }
}

// ================= fused B: H2 = relu(dinv*(gather-sum hs1)+b1); hs2 = bf16((H2@g2W^T)*dinv) =================
__global__ __launch_bounds__(256) void k_agg_gemm2(
    const int* __restrict__ row_off, const int* __restrict__ cnt,
    const int* __restrict__ csr, const float* __restrict__ dinv,
    const unsigned short* __restrict__ hs1, const float* __restrict__ b1,
    const float* __restrict__ Wt, unsigned short* __restrict__ hs2, int N)
{
    __shared__ float s_a[64][APAD];
    const int tid = threadIdx.x;
    const int node0 = blockIdx.x * 64;
    const int qw = tid >> 4, l = tid & 15;   // quarter-wave per node; lane l: dims 8l..8l+7
    const uint4* h4 = (const uint4*)hs1;
    const float4* b4 = (const float4*)b1;
    float4 bb0 = b4[2 * l], bb1 = b4[2 * l + 1];

    #pragma unroll
    for (int p = 0; p < 4; ++p) {
        int m = qw * 4 + p;
        int t = node0 + m;
        float4 A = make_float4(0, 0, 0, 0), B = make_float4(0, 0, 0, 0);
        if (t < N) {
            int beg = row_off[t], len = cnt[t];
            bf_acc(h4[(long)t * 16 + l], A, B);          // self-loop
            int k = 0;
            for (; k + 3 < len; k += 4) {
                int s0 = csr[beg + k],     s1 = csr[beg + k + 1];
                int s2 = csr[beg + k + 2], s3 = csr[beg + k + 3];
                uint4 v0 = h4[(long)s0 * 16 + l];
                uint4 v1 = h4[(long)s1 * 16 + l];
                uint4 v2 = h4[(long)s2 * 16 + l];
                uint4 v3 = h4[(long)s3 * 16 + l];
                bf_acc(v0, A, B); bf_acc(v1, A, B);
                bf_acc(v2, A, B); bf_acc(v3, A, B);
            }
            for (; k < len; ++k) {
                int s0 = csr[beg + k];
                bf_acc(h4[(long)s0 * 16 + l], A, B);
            }
            float di = dinv[t];
            A.x = fmaxf(fmaf(A.x, di, bb0.x), 0.0f);
            A.y = fmaxf(fmaf(A.y, di, bb0.y), 0.0f);
            A.z = fmaxf(fmaf(A.z, di, bb0.z), 0.0f);
            A.w = fmaxf(fmaf(A.w, di, bb0.w), 0.0f);
            B.x = fmaxf(fmaf(B.x, di, bb1.x), 0.0f);
            B.y = fmaxf(fmaf(B.y, di, bb1.y), 0.0f);
            B.z = fmaxf(fmaf(B.z, di, bb1.z), 0.0f);
            B.w = fmaxf(fmaf(B.w, di, bb1.w), 0.0f);
        }
        *((float4*)&s_a[m][8 * l])     = A;
        *((float4*)&s_a[m][8 * l + 4]) = B;
    }
    __syncthreads();

    // gemm2 from LDS
    const int tx = tid & 31;
    const int m0 = (tid >> 5) * 8;
    const float4* Wt4 = (const float4*)Wt;
    float4 c[8];
    #pragma unroll
    for (int j = 0; j < 8; ++j) c[j] = make_float4(0, 0, 0, 0);
    #pragma unroll 2
    for (int k = 0; k < DIM; ++k) {
        float4 w = Wt4[k * 32 + tx];
        #pragma unroll
        for (int j = 0; j < 8; ++j) {
            float a = s_a[m0 + j][k];
            c[j].x = fmaf(a, w.x, c[j].x);
            c[j].y = fmaf(a, w.y, c[j].y);
            c[j].z = fmaf(a, w.z, c[j].z);
            c[j].w = fmaf(a, w.w, c[j].w);
        }
    }
    #pragma unroll
    for (int j = 0; j < 8; ++j) {
        int n = node0 + m0 + j;
        if (n < N) {
            float di = dinv[n];
            ushort4 o;
            o.x = f2bf(c[j].x * di); o.y = f2bf(c[j].y * di);
            o.z = f2bf(c[j].z * di); o.w = f2bf(c[j].w * di);
            ((ushort4*)hs2)[(long)n * 32 + tx] = o;
        }
    }
}

// ================= C: out = relu(dinv*(gather-sum hs2) + b2) (fp32 out) =================
__global__ __launch_bounds__(256) void k_agg_out(
    const int* __restrict__ row_off, const int* __restrict__ cnt,
    const int* __restrict__ csr, const float* __restrict__ dinv,
    const unsigned short* __restrict__ hs2, const float* __restrict__ b2,
    float* __restrict__ out, int N)
{
    int t = blockIdx.x * 16 + (threadIdx.x >> 4);
    int l = threadIdx.x & 15;
    if (t >= N) return;
    const uint4* h4 = (const uint4*)hs2;
    const float4* b4 = (const float4*)b2;
    float4 bb0 = b4[2 * l], bb1 = b4[2 * l + 1];
    float4 A = make_float4(0, 0, 0, 0), B = make_float4(0, 0, 0, 0);
    int beg = row_off[t], len = cnt[t];
    bf_acc(h4[(long)t * 16 + l], A, B);                  // self-loop
    int k = 0;
    for (; k + 3 < len; k += 4) {
        int s0 = csr[beg + k],     s1 = csr[beg + k + 1];
        int s2 = csr[beg + k + 2], s3 = csr[beg + k + 3];
        uint4 v0 = h4[(long)s0 * 16 + l];
        uint4 v1 = h4[(long)s1 * 16 + l];
        uint4 v2 = h4[(long)s2 * 16 + l];
        uint4 v3 = h4[(long)s3 * 16 + l];
        bf_acc(v0, A, B); bf_acc(v1, A, B);
        bf_acc(v2, A, B); bf_acc(v3, A, B);
    }
    for (; k < len; ++k) {
        int s0 = csr[beg + k];
        bf_acc(h4[(long)s0 * 16 + l], A, B);
    }
    float di = dinv[t];
    float4 o0, o1;
    o0.x = fmaxf(fmaf(A.x, di, bb0.x), 0.0f);
    o0.y = fmaxf(fmaf(A.y, di, bb0.y), 0.0f);
    o0.z = fmaxf(fmaf(A.z, di, bb0.z), 0.0f);
    o0.w = fmaxf(fmaf(A.w, di, bb0.w), 0.0f);
    o1.x = fmaxf(fmaf(B.x, di, bb1.x), 0.0f);
    o1.y = fmaxf(fmaf(B.y, di, bb1.y), 0.0f);
    o1.z = fmaxf(fmaf(B.z, di, bb1.z), 0.0f);
    o1.w = fmaxf(fmaf(B.w, di, bb1.w), 0.0f);
    ((float4*)out)[(long)t * 32 + 2 * l]     = o0;
    ((float4*)out)[(long)t * 32 + 2 * l + 1] = o1;
}

extern "C" void kernel_launch(void* const* d_in, const int* in_sizes, int n_in,
                              void* d_out, int out_size, void* d_ws, size_t ws_size,
                              hipStream_t stream) {
    const float* x     = (const float*)d_in[0];
    const int*   edge  = (const int*)d_in[1];
    // d_in[2] = batch (unused)
    const float* emb   = (const float*)d_in[3];
    const float* lin_W = (const float*)d_in[4];
    const float* lin_b = (const float*)d_in[5];
    const float* g1W   = (const float*)d_in[6];
    const float* g1b   = (const float*)d_in[7];
    const float* g2W   = (const float*)d_in[8];
    const float* g2b   = (const float*)d_in[9];
    float* out = (float*)d_out;

    const int N = in_sizes[0] / NFEAT;
    const int E = in_sizes[1] / 2;
    const int* esrc = edge;
    const int* edst = edge + E;

    // workspace carve-up (all (re)initialized every launch)
    float* dinv    = (float*)d_ws;                       // N
    int*   row_off = (int*)(dinv + N);                   // N
    int*   cnt     = row_off + N;                        // N
    int*   cursor  = cnt + N;                            // N
    int*   gbase   = cursor + N;                         // 4
    int*   csr     = gbase + 4;                          // E
    float* linWt   = (float*)(csr + E);                  // 162*128
    float* g1Wt    = linWt + LIN_K * DIM;                // 128*128
    float* g2Wt    = g1Wt + DIM * DIM;                   // 128*128
    float* embWb   = g2Wt + DIM * DIM;                   // 44*128
    unsigned short* hs1 = (unsigned short*)(embWb + NTYPES * DIM);  // N*128 bf16
    unsigned short* hs2 = hs1 + (size_t)N * DIM;                    // N*128 bf16

    const int nb64 = (N + 63) / 64;
    const int nbN  = (N + 255) / 256;
    const int nbE  = (E + 255) / 256;
    const int nbC  = (N + 15) / 16;

    k_transpose_all<<<dim3(24, 3), 256, 0, stream>>>(lin_W, g1W, g2W, linWt, g1Wt, g2Wt);
    k_embW<<<NTYPES, 128, 0, stream>>>(emb, linWt, lin_b, embWb);

    k_zero<<<nbN, 256, 0, stream>>>(cnt, gbase, N);
    k_count<<<nbE, 256, 0, stream>>>(edst, cnt, E);
    k_base<<<nbN, 256, 0, stream>>>(cnt, gbase, row_off, cursor, dinv, N);
    k_fill<<<nbE, 256, 0, stream>>>(esrc, edst, row_off, cursor, csr, E);

    // A: embed + linear + gemm1 -> hs1 (bf16)
    k_embed_gemm1<<<nb64, 256, 0, stream>>>(x, embWb, linWt + DIM * DIM, g1Wt, dinv, hs1, N);
    // B: aggregate layer1 + bias/relu + gemm2 -> hs2 (bf16)
    k_agg_gemm2<<<nb64, 256, 0, stream>>>(row_off, cnt, csr, dinv, hs1, g1b, g2Wt, hs2, N);
    // C: aggregate layer2 + bias/relu -> out (fp32)
    k_agg_out<<<nbC, 256, 0, stream>>>(row_off, cnt, csr, dinv, hs2, g2b, out, N);
}

// Round 6
// 324.116 us; speedup vs baseline: 5.1182x; 1.0484x over previous
//
#include <hip/hip_runtime.h>

#define NFEAT 78
#define NTYPES 44
#define NFIX 34
#define DIM 128
#define LIN_K 162   // DIM + NFIX
#define FIXP 36     // NFIX padded
#define APAD 132    // DIM + 4: LDS row pad
#define TILE 32     // node tile (32 keeps LDS small -> high occupancy; R5's 64 hit the cliff)

typedef unsigned int uint32;

// ---------- bf16 helpers (messages stored bf16, accumulated fp32) ----------
__device__ __forceinline__ unsigned short f2bf(float f) {
    uint32 u = __float_as_uint(f);
    u += 0x7FFFu + ((u >> 16) & 1u);      // round-to-nearest-even
    return (unsigned short)(u >> 16);
}
__device__ __forceinline__ void bf_acc(uint4 v, float4& A, float4& B) {
    A.x += __uint_as_float(v.x << 16); A.y += __uint_as_float(v.x & 0xFFFF0000u);
    A.z += __uint_as_float(v.y << 16); A.w += __uint_as_float(v.y & 0xFFFF0000u);
    B.x += __uint_as_float(v.z << 16); B.y += __uint_as_float(v.z & 0xFFFF0000u);
    B.z += __uint_as_float(v.w << 16); B.w += __uint_as_float(v.w & 0xFFFF0000u);
}

// ================= setup: transpose W's + embWb + zero cnt/gbase (one dispatch) =================
// blocks [0,72): transpose; [72,72+44): embWb from untransposed lin_W; rest: zero cnt
__global__ __launch_bounds__(256) void k_setup(
    const float* __restrict__ w0, const float* __restrict__ w1,
    const float* __restrict__ w2, const float* __restrict__ emb,
    const float* __restrict__ lin_b,
    float* __restrict__ t0, float* __restrict__ t1, float* __restrict__ t2,
    float* __restrict__ embWb, int* __restrict__ cnt, int* __restrict__ gbase, int N)
{
    __shared__ float smem[32 * 33];
    const int bid = blockIdx.x;
    const int tid = threadIdx.x;
    if (bid < 72) {
        // transpose: 24 blocks per matrix
        int sel = bid / 24, b = bid % 24;
        const float* src = sel == 0 ? w0 : (sel == 1 ? w1 : w2);
        float*       dst = sel == 0 ? t0 : (sel == 1 ? t1 : t2);
        const int R = 128;
        const int C = (sel == 0) ? LIN_K : DIM;
        int tc = (C + 31) / 32;
        int bx = b % tc, by = b / tc;
        if (by >= 4) return;                    // block-uniform
        float (*tile)[33] = (float(*)[33])smem;
        int ty = tid >> 5, tx = tid & 31;
        int c0 = bx * 32, r0 = by * 32;
        #pragma unroll
        for (int j = 0; j < 32; j += 8) {
            int r = r0 + ty + j, c = c0 + tx;
            tile[ty + j][tx] = (r < R && c < C) ? src[r * C + c] : 0.0f;
        }
        __syncthreads();
        #pragma unroll
        for (int j = 0; j < 32; j += 8) {
            int c = c0 + ty + j, r = r0 + tx;
            if (c < C && r < R) dst[c * R + r] = tile[tx][ty + j];
        }
    } else if (bid < 72 + NTYPES) {
        // embWb[t][d] = lin_b[d] + sum_k emb[t][k] * lin_W[d][k]  (k < 128)
        int t = bid - 72;
        if (tid < DIM) smem[tid] = emb[t * DIM + tid];
        __syncthreads();
        if (tid < DIM) {
            float acc = lin_b[tid];
            const float* wr = w0 + (long)tid * LIN_K;
            #pragma unroll 4
            for (int k = 0; k < DIM; ++k)
                acc = fmaf(smem[k], wr[k], acc);
            embWb[t * DIM + tid] = acc;
        }
    } else {
        int i = (bid - 72 - NTYPES) * 256 + tid;
        if (i < N) cnt[i] = 0;
        if (i == 0) *gbase = 0;
    }
}

// ================= CSR: count, then scan+dinv =================
__global__ void k_count(const int* __restrict__ dst, int* __restrict__ cnt, int E) {
    int e = blockIdx.x * 256 + threadIdx.x;
    if (e < E) atomicAdd(&cnt[dst[e]], 1);
}
__global__ __launch_bounds__(256) void k_base(
    const int* __restrict__ cnt, int* __restrict__ gbase,
    int* __restrict__ row_off, int* __restrict__ cursor,
    float* __restrict__ dinv, int N)
{
    __shared__ int s[256];
    __shared__ int base;
    int t = threadIdx.x, i = blockIdx.x * 256 + t;
    int c = (i < N) ? cnt[i] : 0;
    s[t] = c;
    __syncthreads();
    for (int off = 1; off < 256; off <<= 1) {
        int u = (t >= off) ? s[t - off] : 0;
        __syncthreads();
        s[t] += u;
        __syncthreads();
    }
    if (t == 255) base = atomicAdd(gbase, s[255]);
    __syncthreads();
    if (i < N) {
        row_off[i] = base + s[t] - c;
        cursor[i] = 0;
        dinv[i] = rsqrtf((float)(c + 1));   // + self-loop
    }
}

// ================= fused: CSR fill (blocks < nbE) || embed+linear+gemm1 (rest) =================
// both depend only on k_base; independent of each other
__global__ __launch_bounds__(256) void k_fill_embed(
    const int* __restrict__ esrc, const int* __restrict__ edst,
    const int* __restrict__ row_off, int* __restrict__ cursor,
    int* __restrict__ csr, int E, int nbE,
    const float* __restrict__ x, const float* __restrict__ embWb,
    const float* __restrict__ W2t, const float* __restrict__ Wt,
    const float* __restrict__ dinv, unsigned short* __restrict__ hs1, int N)
{
    __shared__ float s_fix[TILE][FIXP];
    __shared__ int   s_idx[TILE];
    __shared__ float s_h[TILE][APAD];
    const int tid = threadIdx.x;
    if ((int)blockIdx.x < nbE) {               // ---- CSR fill ----
        int e = blockIdx.x * 256 + tid;
        if (e < E) {
            int t = edst[e];
            int pos = atomicAdd(&cursor[t], 1);
            csr[row_off[t] + pos] = esrc[e];
        }
        return;                                 // block-uniform
    }
    // ---- embed + linear (K=34) + gemm1 ----
    const int node0 = (blockIdx.x - nbE) * TILE;
    if (tid < TILE) {
        int n = node0 + tid;
        int bi = 0;
        if (n < N) {
            const float* xr = x + (long)n * NFEAT;
            float best = xr[0];
            for (int k = 1; k < NTYPES; ++k) {
                float v = xr[k];
                if (v > best) { best = v; bi = k; }   // strict >: first max (jnp.argmax)
            }
        }
        s_idx[tid] = bi;
    }
    for (int q = tid; q < TILE * NFIX; q += 256) {
        int m = q / NFIX, c = q - m * NFIX;
        int n = node0 + m;
        s_fix[m][c] = (n < N) ? x[(long)n * NFEAT + NTYPES + c] : 0.0f;
    }
    __syncthreads();

    const int tx = tid & 31;       // 4 dims: 4tx..4tx+3
    const int m0 = (tid >> 5) * 4; // 4 nodes
    const float4* W2t4 = (const float4*)W2t;
    const float4* eb4  = (const float4*)embWb;
    float4 acc[4];
    #pragma unroll
    for (int j = 0; j < 4; ++j) acc[j] = eb4[s_idx[m0 + j] * 32 + tx];
    #pragma unroll 2
    for (int k = 0; k < NFIX; ++k) {
        float4 w = W2t4[k * 32 + tx];
        #pragma unroll
        for (int j = 0; j < 4; ++j) {
            float a = s_fix[m0 + j][k];
            acc[j].x = fmaf(a, w.x, acc[j].x);
            acc[j].y = fmaf(a, w.y, acc[j].y);
            acc[j].z = fmaf(a, w.z, acc[j].z);
            acc[j].w = fmaf(a, w.w, acc[j].w);
        }
    }
    #pragma unroll
    for (int j = 0; j < 4; ++j) {
        float4 o;
        o.x = fmaxf(acc[j].x, 0.0f); o.y = fmaxf(acc[j].y, 0.0f);
        o.z = fmaxf(acc[j].z, 0.0f); o.w = fmaxf(acc[j].w, 0.0f);
        *((float4*)&s_h[m0 + j][4 * tx]) = o;
    }
    __syncthreads();

    const float4* Wt4 = (const float4*)Wt;
    float4 c[4];
    #pragma unroll
    for (int j = 0; j < 4; ++j) c[j] = make_float4(0, 0, 0, 0);
    #pragma unroll 2
    for (int k = 0; k < DIM; ++k) {
        float4 w = Wt4[k * 32 + tx];
        #pragma unroll
        for (int j = 0; j < 4; ++j) {
            float a = s_h[m0 + j][k];
            c[j].x = fmaf(a, w.x, c[j].x);
            c[j].y = fmaf(a, w.y, c[j].y);
            c[j].z = fmaf(a, w.z, c[j].z);
            c[j].w = fmaf(a, w.w, c[j].w);
        }
    }
    #pragma unroll
    for (int j = 0; j < 4; ++j) {
        int n = node0 + m0 + j;
        if (n < N) {
            float di = dinv[n];
            ushort4 o;
            o.x = f2bf(c[j].x * di); o.y = f2bf(c[j].y * di);
            o.z = f2bf(c[j].z * di); o.w = f2bf(c[j].w * di);
            ((ushort4*)hs1)[(long)n * 32 + tx] = o;
        }
    }
}

// ================= fused B: H2 = relu(dinv*agg(hs1)+b1); hs2 = bf16((H2@g2W^T)*dinv) =================
// 32-node tile -> 16.9 KB LDS -> ~8 blocks/CU for gather latency hiding
__global__ __launch_bounds__(256) void k_agg_gemm2(
    const int* __restrict__ row_off, const int* __restrict__ cnt,
    const int* __restrict__ csr, const float* __restrict__ dinv,
    const unsigned short* __restrict__ hs1, const float* __restrict__ b1,
    const float* __restrict__ Wt, unsigned short* __restrict__ hs2, int N)
{
    __shared__ float s_a[TILE][APAD];
    const int tid = threadIdx.x;
    const int node0 = blockIdx.x * TILE;
    const int qw = tid >> 4, l = tid & 15;   // 16-lane group; lane l: dims 8l..8l+7
    const uint4* h4 = (const uint4*)hs1;
    const float4* b4 = (const float4*)b1;
    float4 bb0 = b4[2 * l], bb1 = b4[2 * l + 1];

    #pragma unroll
    for (int p = 0; p < 2; ++p) {
        int m = qw * 2 + p;
        int t = node0 + m;
        float4 A = make_float4(0, 0, 0, 0), B = make_float4(0, 0, 0, 0);
        if (t < N) {
            int beg = row_off[t], len = cnt[t];
            bf_acc(h4[(long)t * 16 + l], A, B);          // self-loop
            int k = 0;
            for (; k + 3 < len; k += 4) {
                int s0 = csr[beg + k],     s1 = csr[beg + k + 1];
                int s2 = csr[beg + k + 2], s3 = csr[beg + k + 3];
                uint4 v0 = h4[(long)s0 * 16 + l];
                uint4 v1 = h4[(long)s1 * 16 + l];
                uint4 v2 = h4[(long)s2 * 16 + l];
                uint4 v3 = h4[(long)s3 * 16 + l];
                bf_acc(v0, A, B); bf_acc(v1, A, B);
                bf_acc(v2, A, B); bf_acc(v3, A, B);
            }
            for (; k < len; ++k)
                bf_acc(h4[(long)csr[beg + k] * 16 + l], A, B);
            float di = dinv[t];
            A.x = fmaxf(fmaf(A.x, di, bb0.x), 0.0f);
            A.y = fmaxf(fmaf(A.y, di, bb0.y), 0.0f);
            A.z = fmaxf(fmaf(A.z, di, bb0.z), 0.0f);
            A.w = fmaxf(fmaf(A.w, di, bb0.w), 0.0f);
            B.x = fmaxf(fmaf(B.x, di, bb1.x), 0.0f);
            B.y = fmaxf(fmaf(B.y, di, bb1.y), 0.0f);
            B.z = fmaxf(fmaf(B.z, di, bb1.z), 0.0f);
            B.w = fmaxf(fmaf(B.w, di, bb1.w), 0.0f);
        }
        *((float4*)&s_a[m][8 * l])     = A;
        *((float4*)&s_a[m][8 * l + 4]) = B;
    }
    __syncthreads();

    const int tx = tid & 31;
    const int m0 = (tid >> 5) * 4;
    const float4* Wt4 = (const float4*)Wt;
    float4 c[4];
    #pragma unroll
    for (int j = 0; j < 4; ++j) c[j] = make_float4(0, 0, 0, 0);
    #pragma unroll 2
    for (int k = 0; k < DIM; ++k) {
        float4 w = Wt4[k * 32 + tx];
        #pragma unroll
        for (int j = 0; j < 4; ++j) {
            float a = s_a[m0 + j][k];
            c[j].x = fmaf(a, w.x, c[j].x);
            c[j].y = fmaf(a, w.y, c[j].y);
            c[j].z = fmaf(a, w.z, c[j].z);
            c[j].w = fmaf(a, w.w, c[j].w);
        }
    }
    #pragma unroll
    for (int j = 0; j < 4; ++j) {
        int n = node0 + m0 + j;
        if (n < N) {
            float di = dinv[n];
            ushort4 o;
            o.x = f2bf(c[j].x * di); o.y = f2bf(c[j].y * di);
            o.z = f2bf(c[j].z * di); o.w = f2bf(c[j].w * di);
            ((ushort4*)hs2)[(long)n * 32 + tx] = o;
        }
    }
}

// ================= C: out = relu(dinv*agg(hs2) + b2) (fp32 out) =================
__global__ __launch_bounds__(256) void k_agg_out(
    const int* __restrict__ row_off, const int* __restrict__ cnt,
    const int* __restrict__ csr, const float* __restrict__ dinv,
    const unsigned short* __restrict__ hs2, const float* __restrict__ b2,
    float* __restrict__ out, int N)
{
    int t = blockIdx.x * 16 + (threadIdx.x >> 4);
    int l = threadIdx.x & 15;
    if (t >= N) return;
    const uint4* h4 = (const uint4*)hs2;
    const float4* b4 = (const float4*)b2;
    float4 bb0 = b4[2 * l], bb1 = b4[2 * l + 1];
    float4 A = make_float4(0, 0, 0, 0), B = make_float4(0, 0, 0, 0);
    int beg = row_off[t], len = cnt[t];
    bf_acc(h4[(long)t * 16 + l], A, B);                  // self-loop
    int k = 0;
    for (; k + 3 < len; k += 4) {
        int s0 = csr[beg + k],     s1 = csr[beg + k + 1];
        int s2 = csr[beg + k + 2], s3 = csr[beg + k + 3];
        uint4 v0 = h4[(long)s0 * 16 + l];
        uint4 v1 = h4[(long)s1 * 16 + l];
        uint4 v2 = h4[(long)s2 * 16 + l];
        uint4 v3 = h4[(long)s3 * 16 + l];
        bf_acc(v0, A, B); bf_acc(v1, A, B);
        bf_acc(v2, A, B); bf_acc(v3, A, B);
    }
    for (; k < len; ++k)
        bf_acc(h4[(long)csr[beg + k] * 16 + l], A, B);
    float di = dinv[t];
    float4 o0, o1;
    o0.x = fmaxf(fmaf(A.x, di, bb0.x), 0.0f);
    o0.y = fmaxf(fmaf(A.y, di, bb0.y), 0.0f);
    o0.z = fmaxf(fmaf(A.z, di, bb0.z), 0.0f);
    o0.w = fmaxf(fmaf(A.w, di, bb0.w), 0.0f);
    o1.x = fmaxf(fmaf(B.x, di, bb1.x), 0.0f);
    o1.y = fmaxf(fmaf(B.y, di, bb1.y), 0.0f);
    o1.z = fmaxf(fmaf(B.z, di, bb1.z), 0.0f);
    o1.w = fmaxf(fmaf(B.w, di, bb1.w), 0.0f);
    ((float4*)out)[(long)t * 32 + 2 * l]     = o0;
    ((float4*)out)[(long)t * 32 + 2 * l + 1] = o1;
}

extern "C" void kernel_launch(void* const* d_in, const int* in_sizes, int n_in,
                              void* d_out, int out_size, void* d_ws, size_t ws_size,
                              hipStream_t stream) {
    const float* x     = (const float*)d_in[0];
    const int*   edge  = (const int*)d_in[1];
    // d_in[2] = batch (unused)
    const float* emb   = (const float*)d_in[3];
    const float* lin_W = (const float*)d_in[4];
    const float* lin_b = (const float*)d_in[5];
    const float* g1W   = (const float*)d_in[6];
    const float* g1b   = (const float*)d_in[7];
    const float* g2W   = (const float*)d_in[8];
    const float* g2b   = (const float*)d_in[9];
    float* out = (float*)d_out;

    const int N = in_sizes[0] / NFEAT;
    const int E = in_sizes[1] / 2;
    const int* esrc = edge;
    const int* edst = edge + E;

    // workspace carve-up (all (re)initialized every launch)
    float* dinv    = (float*)d_ws;                       // N
    int*   row_off = (int*)(dinv + N);                   // N
    int*   cnt     = row_off + N;                        // N
    int*   cursor  = cnt + N;                            // N
    int*   gbase   = cursor + N;                         // 4
    int*   csr     = gbase + 4;                          // E
    float* linWt   = (float*)(csr + E);                  // 162*128
    float* g1Wt    = linWt + LIN_K * DIM;                // 128*128
    float* g2Wt    = g1Wt + DIM * DIM;                   // 128*128
    float* embWb   = g2Wt + DIM * DIM;                   // 44*128
    unsigned short* hs1 = (unsigned short*)(embWb + NTYPES * DIM);  // N*128 bf16
    unsigned short* hs2 = hs1 + (size_t)N * DIM;                    // N*128 bf16

    const int nbN  = (N + 255) / 256;
    const int nbE  = (E + 255) / 256;
    const int nb32 = (N + TILE - 1) / TILE;
    const int nbC  = (N + 15) / 16;

    // 1: transpose + embWb + zero (merged)
    k_setup<<<72 + NTYPES + nbN, 256, 0, stream>>>(
        lin_W, g1W, g2W, emb, lin_b, linWt, g1Wt, g2Wt, embWb, cnt, gbase, N);
    // 2: degree count
    k_count<<<nbE, 256, 0, stream>>>(edst, cnt, E);
    // 3: scan -> row_off, cursor, dinv
    k_base<<<nbN, 256, 0, stream>>>(cnt, gbase, row_off, cursor, dinv, N);
    // 4: CSR fill || embed+linear+gemm1 -> hs1 (merged, both depend only on k_base)
    k_fill_embed<<<nbE + nb32, 256, 0, stream>>>(
        esrc, edst, row_off, cursor, csr, E, nbE,
        x, embWb, linWt + DIM * DIM, g1Wt, dinv, hs1, N);
    // 5: aggregate L1 + bias/relu + gemm2 -> hs2
    k_agg_gemm2<<<nb32, 256, 0, stream>>>(row_off, cnt, csr, dinv, hs1, g1b, g2Wt, hs2, N);
    // 6: aggregate L2 + bias/relu -> out
    k_agg_out<<<nbC, 256, 0, stream>>>(row_off, cnt, csr, dinv, hs2, g2b, out, N);
}

// Round 7
// 321.535 us; speedup vs baseline: 5.1593x; 1.0080x over previous
//
#include <hip/hip_runtime.h>

#define NFEAT 78
#define NTYPES 44
#define NFIX 34
#define DIM 128
#define LIN_K 162   // DIM + NFIX
#define FIXP 36     // NFIX padded
#define APAD 132    // DIM + 4: LDS row pad
#define TILE 32     // node tile (LDS small -> high occupancy)
#define FILL_CH 2048
#define WSH 13      // dst window = dst >> 13 (8192 nodes/window; 8 windows, XCD-affine)

typedef unsigned int uint32;

// ---------- bf16 helpers (messages stored bf16 UNSCALED, fp32 accumulate) ----------
__device__ __forceinline__ unsigned short f2bf(float f) {
    uint32 u = __float_as_uint(f);
    u += 0x7FFFu + ((u >> 16) & 1u);      // round-to-nearest-even
    return (unsigned short)(u >> 16);
}
// A/B += bf16row(v) * d
__device__ __forceinline__ void bf_fma(uint4 v, float d, float4& A, float4& B) {
    A.x = fmaf(__uint_as_float(v.x << 16),         d, A.x);
    A.y = fmaf(__uint_as_float(v.x & 0xFFFF0000u), d, A.y);
    A.z = fmaf(__uint_as_float(v.y << 16),         d, A.z);
    A.w = fmaf(__uint_as_float(v.y & 0xFFFF0000u), d, A.w);
    B.x = fmaf(__uint_as_float(v.z << 16),         d, B.x);
    B.y = fmaf(__uint_as_float(v.z & 0xFFFF0000u), d, B.y);
    B.z = fmaf(__uint_as_float(v.w << 16),         d, B.z);
    B.w = fmaf(__uint_as_float(v.w & 0xFFFF0000u), d, B.w);
}

// ================= setup: degree count || transpose W's || embWb (one dispatch) =================
// cnt/gbase pre-zeroed by hipMemsetAsync. blocks [0,nbE): count; [nbE,nbE+72): transpose; rest: embWb
__global__ __launch_bounds__(256) void k_setup(
    const int* __restrict__ edst, int* __restrict__ cnt, int E, int nbE,
    const float* __restrict__ w0, const float* __restrict__ w1,
    const float* __restrict__ w2, const float* __restrict__ emb,
    const float* __restrict__ lin_b,
    float* __restrict__ t0, float* __restrict__ t1, float* __restrict__ t2,
    float* __restrict__ embWb)
{
    __shared__ float smem[32 * 33];
    const int bid = blockIdx.x;
    const int tid = threadIdx.x;
    if (bid < nbE) {                            // ---- degree count ----
        int e = bid * 256 + tid;
        if (e < E) atomicAdd(&cnt[edst[e]], 1);
        return;
    }
    if (bid < nbE + 72) {                       // ---- transpose: 24 blocks/matrix ----
        int bb = bid - nbE;
        int sel = bb / 24, b = bb % 24;
        const float* src = sel == 0 ? w0 : (sel == 1 ? w1 : w2);
        float*       dst = sel == 0 ? t0 : (sel == 1 ? t1 : t2);
        const int R = 128;
        const int C = (sel == 0) ? LIN_K : DIM;
        int tc = (C + 31) / 32;
        int bx = b % tc, by = b / tc;
        if (by >= 4) return;                    // block-uniform
        float (*tile)[33] = (float(*)[33])smem;
        int ty = tid >> 5, tx = tid & 31;
        int c0 = bx * 32, r0 = by * 32;
        #pragma unroll
        for (int j = 0; j < 32; j += 8) {
            int r = r0 + ty + j, c = c0 + tx;
            tile[ty + j][tx] = (r < R && c < C) ? src[r * C + c] : 0.0f;
        }
        __syncthreads();
        #pragma unroll
        for (int j = 0; j < 32; j += 8) {
            int c = c0 + ty + j, r = r0 + tx;
            if (c < C && r < R) dst[c * R + r] = tile[tx][ty + j];
        }
        return;
    }
    // ---- embWb[t][d] = lin_b[d] + sum_{k<128} emb[t][k] * lin_W[d][k] ----
    int t = bid - nbE - 72;
    if (tid < DIM) smem[tid] = emb[t * DIM + tid];
    __syncthreads();
    if (tid < DIM) {
        float acc = lin_b[tid];
        const float* wr = w0 + (long)tid * LIN_K;
        #pragma unroll 4
        for (int k = 0; k < DIM; ++k)
            acc = fmaf(smem[k], wr[k], acc);
        embWb[t * DIM + tid] = acc;
    }
}

// ================= scan -> row_off, cursor=0, dinv =================
__global__ __launch_bounds__(256) void k_base(
    const int* __restrict__ cnt, int* __restrict__ gbase,
    int* __restrict__ row_off, int* __restrict__ cursor,
    float* __restrict__ dinv, int N)
{
    __shared__ int s[256];
    __shared__ int base;
    int t = threadIdx.x, i = blockIdx.x * 256 + t;
    int c = (i < N) ? cnt[i] : 0;
    s[t] = c;
    __syncthreads();
    for (int off = 1; off < 256; off <<= 1) {
        int u = (t >= off) ? s[t - off] : 0;
        __syncthreads();
        s[t] += u;
        __syncthreads();
    }
    if (t == 255) base = atomicAdd(gbase, s[255]);
    __syncthreads();
    if (i < N) {
        row_off[i] = base + s[t] - c;
        cursor[i] = 0;
        dinv[i] = rsqrtf((float)(c + 1));   // + self-loop
    }
}

// ================= fused: XCD-affine windowed CSR fill || embed+linear+gemm1 =================
// fill block b: edge chunk b>>3, dst-window b&7 -> each window's cursor/csr region is
// written by one XCD (if blockIdx%8 == XCD), so lines accumulate in one L2 before writeback.
__global__ __launch_bounds__(256) void k_fill_embed(
    const int* __restrict__ esrc, const int* __restrict__ edst,
    const int* __restrict__ row_off, int* __restrict__ cursor,
    int* __restrict__ csr, int E, int nbF,
    const float* __restrict__ x, const float* __restrict__ embWb,
    const float* __restrict__ W2t, const float* __restrict__ Wt,
    unsigned short* __restrict__ hs1, int N)
{
    __shared__ float s_fix[TILE][FIXP];
    __shared__ int   s_idx[TILE];
    __shared__ float s_h[TILE][APAD];
    const int tid = threadIdx.x;
    if ((int)blockIdx.x < nbF) {               // ---- windowed CSR fill ----
        int w = blockIdx.x & 7;
        int base = (blockIdx.x >> 3) * FILL_CH;
        int end = base + FILL_CH; if (end > E) end = E;
        for (int i = base + tid; i < end; i += 256) {
            int t = edst[i];
            if ((t >> WSH) == w) {
                int pos = atomicAdd(&cursor[t], 1);
                csr[row_off[t] + pos] = esrc[i];
            }
        }
        return;                                 // block-uniform
    }
    // ---- embed + linear (K=34) + gemm1, hs1 unscaled ----
    const int node0 = (blockIdx.x - nbF) * TILE;
    if (tid < TILE) {
        int n = node0 + tid;
        int bi = 0;
        if (n < N) {
            const float* xr = x + (long)n * NFEAT;
            float best = xr[0];
            for (int k = 1; k < NTYPES; ++k) {
                float v = xr[k];
                if (v > best) { best = v; bi = k; }   // strict >: first max (jnp.argmax)
            }
        }
        s_idx[tid] = bi;
    }
    for (int q = tid; q < TILE * NFIX; q += 256) {
        int m = q / NFIX, c = q - m * NFIX;
        int n = node0 + m;
        s_fix[m][c] = (n < N) ? x[(long)n * NFEAT + NTYPES + c] : 0.0f;
    }
    __syncthreads();

    const int tx = tid & 31;       // 4 dims: 4tx..4tx+3
    const int m0 = (tid >> 5) * 4; // 4 nodes
    const float4* W2t4 = (const float4*)W2t;
    const float4* eb4  = (const float4*)embWb;
    float4 acc[4];
    #pragma unroll
    for (int j = 0; j < 4; ++j) acc[j] = eb4[s_idx[m0 + j] * 32 + tx];
    // K=34: 32 by 4 + tail 2; batch W loads ahead of FMAs for ILP
    for (int k = 0; k < 32; k += 4) {
        float4 w0 = W2t4[(k + 0) * 32 + tx];
        float4 w1 = W2t4[(k + 1) * 32 + tx];
        float4 w2 = W2t4[(k + 2) * 32 + tx];
        float4 w3 = W2t4[(k + 3) * 32 + tx];
        #pragma unroll
        for (int j = 0; j < 4; ++j) {
            float a0 = s_fix[m0 + j][k], a1 = s_fix[m0 + j][k + 1];
            float a2 = s_fix[m0 + j][k + 2], a3 = s_fix[m0 + j][k + 3];
            acc[j].x = fmaf(a3, w3.x, fmaf(a2, w2.x, fmaf(a1, w1.x, fmaf(a0, w0.x, acc[j].x))));
            acc[j].y = fmaf(a3, w3.y, fmaf(a2, w2.y, fmaf(a1, w1.y, fmaf(a0, w0.y, acc[j].y))));
            acc[j].z = fmaf(a3, w3.z, fmaf(a2, w2.z, fmaf(a1, w1.z, fmaf(a0, w0.z, acc[j].z))));
            acc[j].w = fmaf(a3, w3.w, fmaf(a2, w2.w, fmaf(a1, w1.w, fmaf(a0, w0.w, acc[j].w))));
        }
    }
    {
        float4 w0 = W2t4[32 * 32 + tx];
        float4 w1 = W2t4[33 * 32 + tx];
        #pragma unroll
        for (int j = 0; j < 4; ++j) {
            float a0 = s_fix[m0 + j][32], a1 = s_fix[m0 + j][33];
            acc[j].x = fmaf(a1, w1.x, fmaf(a0, w0.x, acc[j].x));
            acc[j].y = fmaf(a1, w1.y, fmaf(a0, w0.y, acc[j].y));
            acc[j].z = fmaf(a1, w1.z, fmaf(a0, w0.z, acc[j].z));
            acc[j].w = fmaf(a1, w1.w, fmaf(a0, w0.w, acc[j].w));
        }
    }
    #pragma unroll
    for (int j = 0; j < 4; ++j) {
        float4 o;
        o.x = fmaxf(acc[j].x, 0.0f); o.y = fmaxf(acc[j].y, 0.0f);
        o.z = fmaxf(acc[j].z, 0.0f); o.w = fmaxf(acc[j].w, 0.0f);
        *((float4*)&s_h[m0 + j][4 * tx]) = o;
    }
    __syncthreads();

    const float4* Wt4 = (const float4*)Wt;
    float4 c[4];
    #pragma unroll
    for (int j = 0; j < 4; ++j) c[j] = make_float4(0, 0, 0, 0);
    for (int k = 0; k < DIM; k += 4) {
        float4 w0 = Wt4[(k + 0) * 32 + tx];
        float4 w1 = Wt4[(k + 1) * 32 + tx];
        float4 w2 = Wt4[(k + 2) * 32 + tx];
        float4 w3 = Wt4[(k + 3) * 32 + tx];
        #pragma unroll
        for (int j = 0; j < 4; ++j) {
            float a0 = s_h[m0 + j][k], a1 = s_h[m0 + j][k + 1];
            float a2 = s_h[m0 + j][k + 2], a3 = s_h[m0 + j][k + 3];
            c[j].x = fmaf(a3, w3.x, fmaf(a2, w2.x, fmaf(a1, w1.x, fmaf(a0, w0.x, c[j].x))));
            c[j].y = fmaf(a3, w3.y, fmaf(a2, w2.y, fmaf(a1, w1.y, fmaf(a0, w0.y, c[j].y))));
            c[j].z = fmaf(a3, w3.z, fmaf(a2, w2.z, fmaf(a1, w1.z, fmaf(a0, w0.z, c[j].z))));
            c[j].w = fmaf(a3, w3.w, fmaf(a2, w2.w, fmaf(a1, w1.w, fmaf(a0, w0.w, c[j].w))));
        }
    }
    #pragma unroll
    for (int j = 0; j < 4; ++j) {
        int n = node0 + m0 + j;
        if (n < N) {
            ushort4 o;
            o.x = f2bf(c[j].x); o.y = f2bf(c[j].y);
            o.z = f2bf(c[j].z); o.w = f2bf(c[j].w);
            ((ushort4*)hs1)[(long)n * 32 + tx] = o;
        }
    }
}

// ================= fused B: H2 = relu(dinv_t*agg(dinv_s*hs1)+b1); hs2 = bf16(H2@g2W^T) =================
__global__ __launch_bounds__(256) void k_agg_gemm2(
    const int* __restrict__ row_off, const int* __restrict__ cnt,
    const int* __restrict__ csr, const float* __restrict__ dinv,
    const unsigned short* __restrict__ hs1, const float* __restrict__ b1,
    const float* __restrict__ Wt, unsigned short* __restrict__ hs2, int N)
{
    __shared__ float s_a[TILE][APAD];
    const int tid = threadIdx.x;
    const int node0 = blockIdx.x * TILE;
    const int qw = tid >> 4, l = tid & 15;   // 16-lane group; lane l: dims 8l..8l+7
    const uint4* h4 = (const uint4*)hs1;
    const float4* b4 = (const float4*)b1;
    float4 bb0 = b4[2 * l], bb1 = b4[2 * l + 1];

    #pragma unroll
    for (int p = 0; p < 2; ++p) {
        int m = qw * 2 + p;
        int t = node0 + m;
        float4 A = make_float4(0, 0, 0, 0), B = make_float4(0, 0, 0, 0);
        if (t < N) {
            int beg = row_off[t], len = cnt[t];
            float dt = dinv[t];
            bf_fma(h4[(long)t * 16 + l], dt, A, B);      // self-loop
            int k = 0;
            for (; k + 3 < len; k += 4) {
                int s0 = csr[beg + k],     s1 = csr[beg + k + 1];
                int s2 = csr[beg + k + 2], s3 = csr[beg + k + 3];
                float d0 = dinv[s0], d1 = dinv[s1], d2 = dinv[s2], d3 = dinv[s3];
                uint4 v0 = h4[(long)s0 * 16 + l];
                uint4 v1 = h4[(long)s1 * 16 + l];
                uint4 v2 = h4[(long)s2 * 16 + l];
                uint4 v3 = h4[(long)s3 * 16 + l];
                bf_fma(v0, d0, A, B); bf_fma(v1, d1, A, B);
                bf_fma(v2, d2, A, B); bf_fma(v3, d3, A, B);
            }
            for (; k < len; ++k) {
                int s0 = csr[beg + k];
                bf_fma(h4[(long)s0 * 16 + l], dinv[s0], A, B);
            }
            A.x = fmaxf(fmaf(A.x, dt, bb0.x), 0.0f);
            A.y = fmaxf(fmaf(A.y, dt, bb0.y), 0.0f);
            A.z = fmaxf(fmaf(A.z, dt, bb0.z), 0.0f);
            A.w = fmaxf(fmaf(A.w, dt, bb0.w), 0.0f);
            B.x = fmaxf(fmaf(B.x, dt, bb1.x), 0.0f);
            B.y = fmaxf(fmaf(B.y, dt, bb1.y), 0.0f);
            B.z = fmaxf(fmaf(B.z, dt, bb1.z), 0.0f);
            B.w = fmaxf(fmaf(B.w, dt, bb1.w), 0.0f);
        }
        *((float4*)&s_a[m][8 * l])     = A;
        *((float4*)&s_a[m][8 * l + 4]) = B;
    }
    __syncthreads();

    const int tx = tid & 31;
    const int m0 = (tid >> 5) * 4;
    const float4* Wt4 = (const float4*)Wt;
    float4 c[4];
    #pragma unroll
    for (int j = 0; j < 4; ++j) c[j] = make_float4(0, 0, 0, 0);
    for (int k = 0; k < DIM; k += 4) {
        float4 w0 = Wt4[(k + 0) * 32 + tx];
        float4 w1 = Wt4[(k + 1) * 32 + tx];
        float4 w2 = Wt4[(k + 2) * 32 + tx];
        float4 w3 = Wt4[(k + 3) * 32 + tx];
        #pragma unroll
        for (int j = 0; j < 4; ++j) {
            float a0 = s_a[m0 + j][k], a1 = s_a[m0 + j][k + 1];
            float a2 = s_a[m0 + j][k + 2], a3 = s_a[m0 + j][k + 3];
            c[j].x = fmaf(a3, w3.x, fmaf(a2, w2.x, fmaf(a1, w1.x, fmaf(a0, w0.x, c[j].x))));
            c[j].y = fmaf(a3, w3.y, fmaf(a2, w2.y, fmaf(a1, w1.y, fmaf(a0, w0.y, c[j].y))));
            c[j].z = fmaf(a3, w3.z, fmaf(a2, w2.z, fmaf(a1, w1.z, fmaf(a0, w0.z, c[j].z))));
            c[j].w = fmaf(a3, w3.w, fmaf(a2, w2.w, fmaf(a1, w1.w, fmaf(a0, w0.w, c[j].w))));
        }
    }
    #pragma unroll
    for (int j = 0; j < 4; ++j) {
        int n = node0 + m0 + j;
        if (n < N) {
            ushort4 o;
            o.x = f2bf(c[j].x); o.y = f2bf(c[j].y);
            o.z = f2bf(c[j].z); o.w = f2bf(c[j].w);
            ((ushort4*)hs2)[(long)n * 32 + tx] = o;
        }
    }
}

// ================= C: out = relu(dinv_t*agg(dinv_s*hs2) + b2) (fp32) =================
__global__ __launch_bounds__(256) void k_agg_out(
    const int* __restrict__ row_off, const int* __restrict__ cnt,
    const int* __restrict__ csr, const float* __restrict__ dinv,
    const unsigned short* __restrict__ hs2, const float* __restrict__ b2,
    float* __restrict__ out, int N)
{
    int t = blockIdx.x * 16 + (threadIdx.x >> 4);
    int l = threadIdx.x & 15;
    if (t >= N) return;
    const uint4* h4 = (const uint4*)hs2;
    const float4* b4 = (const float4*)b2;
    float4 bb0 = b4[2 * l], bb1 = b4[2 * l + 1];
    float4 A = make_float4(0, 0, 0, 0), B = make_float4(0, 0, 0, 0);
    int beg = row_off[t], len = cnt[t];
    float dt = dinv[t];
    bf_fma(h4[(long)t * 16 + l], dt, A, B);              // self-loop
    int k = 0;
    for (; k + 3 < len; k += 4) {
        int s0 = csr[beg + k],     s1 = csr[beg + k + 1];
        int s2 = csr[beg + k + 2], s3 = csr[beg + k + 3];
        float d0 = dinv[s0], d1 = dinv[s1], d2 = dinv[s2], d3 = dinv[s3];
        uint4 v0 = h4[(long)s0 * 16 + l];
        uint4 v1 = h4[(long)s1 * 16 + l];
        uint4 v2 = h4[(long)s2 * 16 + l];
        uint4 v3 = h4[(long)s3 * 16 + l];
        bf_fma(v0, d0, A, B); bf_fma(v1, d1, A, B);
        bf_fma(v2, d2, A, B); bf_fma(v3, d3, A, B);
    }
    for (; k < len; ++k) {
        int s0 = csr[beg + k];
        bf_fma(h4[(long)s0 * 16 + l], dinv[s0], A, B);
    }
    float4 o0, o1;
    o0.x = fmaxf(fmaf(A.x, dt, bb0.x), 0.0f);
    o0.y = fmaxf(fmaf(A.y, dt, bb0.y), 0.0f);
    o0.z = fmaxf(fmaf(A.z, dt, bb0.z), 0.0f);
    o0.w = fmaxf(fmaf(A.w, dt, bb0.w), 0.0f);
    o1.x = fmaxf(fmaf(B.x, dt, bb1.x), 0.0f);
    o1.y = fmaxf(fmaf(B.y, dt, bb1.y), 0.0f);
    o1.z = fmaxf(fmaf(B.z, dt, bb1.z), 0.0f);
    o1.w = fmaxf(fmaf(B.w, dt, bb1.w), 0.0f);
    ((float4*)out)[(long)t * 32 + 2 * l]     = o0;
    ((float4*)out)[(long)t * 32 + 2 * l + 1] = o1;
}

extern "C" void kernel_launch(void* const* d_in, const int* in_sizes, int n_in,
                              void* d_out, int out_size, void* d_ws, size_t ws_size,
                              hipStream_t stream) {
    const float* x     = (const float*)d_in[0];
    const int*   edge  = (const int*)d_in[1];
    // d_in[2] = batch (unused)
    const float* emb   = (const float*)d_in[3];
    const float* lin_W = (const float*)d_in[4];
    const float* lin_b = (const float*)d_in[5];
    const float* g1W   = (const float*)d_in[6];
    const float* g1b   = (const float*)d_in[7];
    const float* g2W   = (const float*)d_in[8];
    const float* g2b   = (const float*)d_in[9];
    float* out = (float*)d_out;

    const int N = in_sizes[0] / NFEAT;
    const int E = in_sizes[1] / 2;
    const int* esrc = edge;
    const int* edst = edge + E;

    // workspace carve-up (all (re)initialized every launch); cnt..gbase contiguous for one memset
    float* dinv    = (float*)d_ws;                       // N
    int*   row_off = (int*)(dinv + N);                   // N
    int*   cursor  = row_off + N;                        // N
    int*   cnt     = cursor + N;                         // N
    int*   gbase   = cnt + N;                            // 1 (+3 pad)
    int*   csr     = gbase + 4;                          // E
    float* linWt   = (float*)(csr + E);                  // 162*128
    float* g1Wt    = linWt + LIN_K * DIM;                // 128*128
    float* g2Wt    = g1Wt + DIM * DIM;                   // 128*128
    float* embWb   = g2Wt + DIM * DIM;                   // 44*128
    unsigned short* hs1 = (unsigned short*)(embWb + NTYPES * DIM);  // N*128 bf16
    unsigned short* hs2 = hs1 + (size_t)N * DIM;                    // N*128 bf16

    const int nbN   = (N + 255) / 256;
    const int nbE   = (E + 255) / 256;
    const int nb32  = (N + TILE - 1) / TILE;
    const int nbC   = (N + 15) / 16;
    const int nbF   = ((E + FILL_CH - 1) / FILL_CH) * 8;   // windowed fill blocks

    // 0: zero cnt + gbase (capturable async memset)
    hipMemsetAsync(cnt, 0, (size_t)(N + 1) * sizeof(int), stream);
    // 1: degree count || transpose || embWb
    k_setup<<<nbE + 72 + NTYPES, 256, 0, stream>>>(
        edst, cnt, E, nbE, lin_W, g1W, g2W, emb, lin_b, linWt, g1Wt, g2Wt, embWb);
    // 2: scan -> row_off, cursor, dinv
    k_base<<<nbN, 256, 0, stream>>>(cnt, gbase, row_off, cursor, dinv, N);
    // 3: windowed CSR fill || embed+linear+gemm1 -> hs1 (unscaled bf16)
    k_fill_embed<<<nbF + nb32, 256, 0, stream>>>(
        esrc, edst, row_off, cursor, csr, E, nbF,
        x, embWb, linWt + DIM * DIM, g1Wt, hs1, N);
    // 4: aggregate L1 + bias/relu + gemm2 -> hs2 (unscaled bf16)
    k_agg_gemm2<<<nb32, 256, 0, stream>>>(row_off, cnt, csr, dinv, hs1, g1b, g2Wt, hs2, N);
    // 5: aggregate L2 + bias/relu -> out (fp32)
    k_agg_out<<<nbC, 256, 0, stream>>>(row_off, cnt, csr, dinv, hs2, g2b, out, N);
}